// Round 1
// baseline (1415.537 us; speedup 1.0000x reference)
//
#include <hip/hip_runtime.h>
#include <float.h>
#include <math.h>

#define T_ 1024
#define D_ 1024
#define H_ 16
#define HD_ 64
#define E_ 8
#define F_ 2560
#define D3_ 3072
#define F2_ 5120

// ---- workspace layout (float offsets) ----
#define WS_H    0u         // 1M   LN1 out
#define WS_QKV  1048576u   // 3M   qkv (T,3D), rope applied in-place
#define WS_ATTN 4194304u   // 1M   attention out (T,D)
#define WS_X2   5242880u   // 1M   x + attn proj (T,D)
#define WS_H2   6291456u   // 1M   LN2 out
#define WS_A    7340032u   // 2.62M  gated activation (T,F)
#define WS_GW   9961472u   // 1024 floats gate weight
#define WS_GI   9962496u   // 1024 ints   gate index
#define WS_OFFS 9963520u   // 16 ints     expert offsets
#define WS_PERM 9963536u   // 1024 ints   token perm grouped by expert
// total ~9.96M floats ~= 40 MB

#define FMA16(ACC, A4, B4) \
  ACC[0][0]+=A4.x*B4.x; ACC[0][1]+=A4.x*B4.y; ACC[0][2]+=A4.x*B4.z; ACC[0][3]+=A4.x*B4.w; \
  ACC[1][0]+=A4.y*B4.x; ACC[1][1]+=A4.y*B4.y; ACC[1][2]+=A4.y*B4.z; ACC[1][3]+=A4.y*B4.w; \
  ACC[2][0]+=A4.z*B4.x; ACC[2][1]+=A4.z*B4.y; ACC[2][2]+=A4.z*B4.z; ACC[2][3]+=A4.z*B4.w; \
  ACC[3][0]+=A4.w*B4.x; ACC[3][1]+=A4.w*B4.y; ACC[3][2]+=A4.w*B4.z; ACC[3][3]+=A4.w*B4.w;

// -------------------- LayerNorm 1 --------------------
__global__ __launch_bounds__(256) void ln_kernel(
    const float* __restrict__ x, const float* __restrict__ w,
    const float* __restrict__ b, float* __restrict__ out)
{
    const int row = blockIdx.x, tid = threadIdx.x;
    const int lane = tid & 63, wave = tid >> 6;
    float4 v = ((const float4*)(x + (size_t)row * D_))[tid];
    float s  = v.x + v.y + v.z + v.w;
    float sq = v.x*v.x + v.y*v.y + v.z*v.z + v.w*v.w;
    #pragma unroll
    for (int off = 32; off; off >>= 1) {
        s  += __shfl_down(s, off);
        sq += __shfl_down(sq, off);
    }
    __shared__ float rs[4], rq[4], mv[2];
    if (lane == 0) { rs[wave] = s; rq[wave] = sq; }
    __syncthreads();
    if (tid == 0) {
        float ts = rs[0]+rs[1]+rs[2]+rs[3];
        float tq = rq[0]+rq[1]+rq[2]+rq[3];
        float mean = ts * (1.0f / D_);
        float var  = tq * (1.0f / D_) - mean*mean;
        mv[0] = mean; mv[1] = rsqrtf(var + 1e-5f);
    }
    __syncthreads();
    float mean = mv[0], rstd = mv[1];
    float4 wv = ((const float4*)w)[tid];
    float4 bv = ((const float4*)b)[tid];
    float4 o;
    o.x = (v.x-mean)*rstd*wv.x + bv.x;
    o.y = (v.y-mean)*rstd*wv.y + bv.y;
    o.z = (v.z-mean)*rstd*wv.z + bv.z;
    o.w = (v.w-mean)*rstd*wv.w + bv.w;
    ((float4*)(out + (size_t)row * D_))[tid] = o;
}

// -------------------- generic fp32 GEMM (NN): C = alpha*A@B (+bias)(+resid) --------------------
__global__ __launch_bounds__(256) void gemm_nn(
    const float* __restrict__ A, int lda, long sA,
    const float* __restrict__ B, int ldb, long sB,
    const float* __restrict__ bias,
    const float* __restrict__ resid,
    float* __restrict__ C, int ldc, long sC,
    int M, int N, int K, float alpha)
{
    const int bz = blockIdx.z;
    A += (long)bz * sA; B += (long)bz * sB; C += (long)bz * sC;
    if (resid) resid += (long)bz * sC;
    const int row0 = blockIdx.y * 64, col0 = blockIdx.x * 64;
    const int tid = threadIdx.x;
    const int tx = tid & 15, ty = tid >> 4;
    __shared__ __align__(16) float As[16][68];
    __shared__ __align__(16) float Bs[16][68];
    float acc[4][4] = {};
    const int am = tid >> 2, ak = (tid & 3) * 4;
    const int bk = tid >> 4, bn = (tid & 15) * 4;
    for (int k0 = 0; k0 < K; k0 += 16) {
        float4 av = *(const float4*)(A + (size_t)(row0+am)*lda + k0 + ak);
        float4 bv = *(const float4*)(B + (size_t)(k0+bk)*ldb + col0 + bn);
        As[ak+0][am]=av.x; As[ak+1][am]=av.y; As[ak+2][am]=av.z; As[ak+3][am]=av.w;
        *(float4*)&Bs[bk][bn] = bv;
        __syncthreads();
        #pragma unroll
        for (int kk = 0; kk < 16; kk++) {
            float4 a4 = *(const float4*)&As[kk][ty*4];
            float4 b4 = *(const float4*)&Bs[kk][tx*4];
            FMA16(acc, a4, b4)
        }
        __syncthreads();
    }
    #pragma unroll
    for (int i = 0; i < 4; i++) {
        int r = row0 + ty*4 + i;
        #pragma unroll
        for (int j = 0; j < 4; j++) {
            int c = col0 + tx*4 + j;
            float v = acc[i][j] * alpha;
            if (bias)  v += bias[c];
            if (resid) v += resid[(size_t)r*ldc + c];
            C[(size_t)r*ldc + c] = v;
        }
    }
}

// -------------------- RoPE in-place on q,k inside qkv --------------------
__global__ __launch_bounds__(256) void rope_kernel(float* __restrict__ qkv)
{
    int gid = blockIdx.x * 256 + threadIdx.x;   // over T*H*32 = 524288
    int t = gid >> 9;
    int r = gid & 511;
    int h = r >> 5;
    int d = r & 31;
    float inv = powf(10000.0f, -(float)d * (1.0f/32.0f));
    float fr = (float)t * inv;
    float s, c;
    sincosf(fr, &s, &c);
    float* base = qkv + (size_t)t*D3_ + h*HD_ + d;
    float q1 = base[0], q2 = base[32];
    base[0]  = q1*c - q2*s;
    base[32] = q1*s + q2*c;
    float* kb = base + D_;
    float k1 = kb[0], k2 = kb[32];
    kb[0]  = k1*c - k2*s;
    kb[32] = k1*s + k2*c;
}

// -------------------- fused attention: 4 queries x 1 head per block --------------------
__global__ __launch_bounds__(256) void attn_kernel(
    const float* __restrict__ qkv, const int* __restrict__ ids,
    float* __restrict__ attnout)
{
    const int h = blockIdx.y;
    const int q0 = blockIdx.x * 4;
    const int tid = threadIdx.x;
    const int lane = tid & 63, wave = tid >> 6;

    __shared__ __align__(16) float qv[4][64];
    __shared__ float pp[4][1024];
    __shared__ float red[4][4];
    __shared__ float bcm[4], bcs[4];
    __shared__ float pv[4][4][64];

    {
        int qi = tid >> 6, d = tid & 63;
        qv[qi][d] = qkv[(size_t)(q0+qi)*D3_ + h*HD_ + d];
    }
    int kmax[4];
    int kall = 0;
    #pragma unroll
    for (int qi = 0; qi < 4; qi++) {
        int id = ids[q0+qi];
        bool glob = (id >= 2 && id <= 7);
        kmax[qi] = glob ? T_ : (q0 + qi + 1);
        kall = max(kall, kmax[qi]);
    }
    __syncthreads();

    // scores
    float mx[4] = {-FLT_MAX, -FLT_MAX, -FLT_MAX, -FLT_MAX};
    #pragma unroll
    for (int i = 0; i < 4; i++) {
        int k = tid + i*256;
        float dot[4] = {0.f, 0.f, 0.f, 0.f};
        if (k < kall) {
            const float* kr = qkv + (size_t)k*D3_ + D_ + h*HD_;
            #pragma unroll
            for (int d = 0; d < 64; d += 4) {
                float4 kv4 = *(const float4*)(kr + d);
                #pragma unroll
                for (int qi = 0; qi < 4; qi++) {
                    float4 q4 = *(const float4*)&qv[qi][d];
                    dot[qi] += q4.x*kv4.x + q4.y*kv4.y + q4.z*kv4.z + q4.w*kv4.w;
                }
            }
        }
        #pragma unroll
        for (int qi = 0; qi < 4; qi++) {
            float l = (k < kmax[qi]) ? dot[qi]*0.125f : -FLT_MAX;
            pp[qi][k] = l;
            mx[qi] = fmaxf(mx[qi], l);
        }
    }
    #pragma unroll
    for (int off = 32; off; off >>= 1)
        #pragma unroll
        for (int qi = 0; qi < 4; qi++)
            mx[qi] = fmaxf(mx[qi], __shfl_down(mx[qi], off));
    if (lane == 0)
        for (int qi = 0; qi < 4; qi++) red[qi][wave] = mx[qi];
    __syncthreads();
    if (tid < 4)
        bcm[tid] = fmaxf(fmaxf(red[tid][0], red[tid][1]), fmaxf(red[tid][2], red[tid][3]));
    __syncthreads();

    float m4[4] = {bcm[0], bcm[1], bcm[2], bcm[3]};
    float sm[4] = {0.f, 0.f, 0.f, 0.f};
    #pragma unroll
    for (int i = 0; i < 4; i++) {
        int k = tid + i*256;
        #pragma unroll
        for (int qi = 0; qi < 4; qi++) {
            float e = expf(pp[qi][k] - m4[qi]);
            pp[qi][k] = e;
            sm[qi] += e;
        }
    }
    #pragma unroll
    for (int off = 32; off; off >>= 1)
        #pragma unroll
        for (int qi = 0; qi < 4; qi++)
            sm[qi] += __shfl_down(sm[qi], off);
    if (lane == 0)
        for (int qi = 0; qi < 4; qi++) red[qi][wave] = sm[qi];
    __syncthreads();
    if (tid < 4)
        bcs[tid] = red[tid][0] + red[tid][1] + red[tid][2] + red[tid][3];
    __syncthreads();

    // PV
    const int tx = tid & 63, ty = tid >> 6;
    float acc[4] = {0.f, 0.f, 0.f, 0.f};
    int kend = min(kall, (ty+1)*256);
    for (int k = ty*256; k < kend; k++) {
        float vv = qkv[(size_t)k*D3_ + 2*D_ + h*HD_ + tx];
        #pragma unroll
        for (int qi = 0; qi < 4; qi++) acc[qi] += pp[qi][k] * vv;
    }
    #pragma unroll
    for (int qi = 0; qi < 4; qi++) pv[ty][qi][tx] = acc[qi];
    __syncthreads();
    if (ty == 0) {
        #pragma unroll
        for (int qi = 0; qi < 4; qi++) {
            float o = (pv[0][qi][tx] + pv[1][qi][tx] + pv[2][qi][tx] + pv[3][qi][tx]) / bcs[qi];
            attnout[(size_t)(q0+qi)*D_ + h*HD_ + tx] = o;
        }
    }
}

// -------------------- LN2 + gate (softmax-top1) --------------------
__global__ __launch_bounds__(256) void ln2_gate_kernel(
    const float* __restrict__ x2, const float* __restrict__ w,
    const float* __restrict__ b, const float* __restrict__ gwm,
    const float* __restrict__ gbv, float* __restrict__ h2,
    int* __restrict__ gi, float* __restrict__ gw)
{
    const int row = blockIdx.x, tid = threadIdx.x;
    const int lane = tid & 63, wave = tid >> 6;
    float4 v = ((const float4*)(x2 + (size_t)row * D_))[tid];
    float s  = v.x + v.y + v.z + v.w;
    float sq = v.x*v.x + v.y*v.y + v.z*v.z + v.w*v.w;
    #pragma unroll
    for (int off = 32; off; off >>= 1) {
        s  += __shfl_down(s, off);
        sq += __shfl_down(sq, off);
    }
    __shared__ float rs[4], rq[4], mv[2];
    if (lane == 0) { rs[wave] = s; rq[wave] = sq; }
    __syncthreads();
    if (tid == 0) {
        float ts = rs[0]+rs[1]+rs[2]+rs[3];
        float tq = rq[0]+rq[1]+rq[2]+rq[3];
        float mean = ts * (1.0f / D_);
        float var  = tq * (1.0f / D_) - mean*mean;
        mv[0] = mean; mv[1] = rsqrtf(var + 1e-5f);
    }
    __syncthreads();
    float mean = mv[0], rstd = mv[1];
    float4 wv = ((const float4*)w)[tid];
    float4 bv = ((const float4*)b)[tid];
    float hv[4];
    hv[0] = (v.x-mean)*rstd*wv.x + bv.x;
    hv[1] = (v.y-mean)*rstd*wv.y + bv.y;
    hv[2] = (v.z-mean)*rstd*wv.z + bv.z;
    hv[3] = (v.w-mean)*rstd*wv.w + bv.w;
    float4 o; o.x=hv[0]; o.y=hv[1]; o.z=hv[2]; o.w=hv[3];
    ((float4*)(h2 + (size_t)row * D_))[tid] = o;

    // gate logits
    float acc[E_] = {};
    int c = tid * 4;
    #pragma unroll
    for (int j = 0; j < 4; j++) {
        const float* gr = gwm + (size_t)(c+j) * E_;
        #pragma unroll
        for (int e = 0; e < E_; e++) acc[e] += hv[j] * gr[e];
    }
    #pragma unroll
    for (int off = 32; off; off >>= 1)
        #pragma unroll
        for (int e = 0; e < E_; e++) acc[e] += __shfl_down(acc[e], off);
    __shared__ float gred[4][E_];
    if (lane == 0)
        for (int e = 0; e < E_; e++) gred[wave][e] = acc[e];
    __syncthreads();
    if (tid == 0) {
        float lg[E_];
        float mxl = -FLT_MAX; int mi = 0;
        for (int e = 0; e < E_; e++)
            lg[e] = gred[0][e]+gred[1][e]+gred[2][e]+gred[3][e] + gbv[e];
        for (int e = 0; e < E_; e++)
            if (lg[e] > mxl) { mxl = lg[e]; mi = e; }   // strict > keeps first max (jnp argmax)
        float ssum = 0.f;
        for (int e = 0; e < E_; e++) ssum += expf(lg[e] - mxl);
        gi[row] = mi;
        gw[row] = 1.0f / ssum;   // max softmax prob = 1/sum(exp(l - lmax))
    }
}

// -------------------- token routing: group by expert --------------------
__global__ void route_kernel(const int* __restrict__ gi,
                             int* __restrict__ offs, int* __restrict__ perm)
{
    __shared__ int cnt[E_], c2[E_], off[E_+1];
    const int tid = threadIdx.x;
    if (tid < E_) { cnt[tid] = 0; c2[tid] = 0; }
    __syncthreads();
    int e = gi[tid];
    atomicAdd(&cnt[e], 1);
    __syncthreads();
    if (tid == 0) {
        off[0] = 0;
        for (int i = 0; i < E_; i++) off[i+1] = off[i] + cnt[i];
        for (int i = 0; i <= E_; i++) offs[i] = off[i];
    }
    __syncthreads();
    int r = atomicAdd(&c2[e], 1);
    perm[off[e] + r] = tid;
}

// -------------------- grouped MoE fc GEMM + GLU(exact gelu) --------------------
__global__ __launch_bounds__(256) void moe_fc_kernel(
    const float* __restrict__ h2, const float* __restrict__ fcw,
    const float* __restrict__ fcb, const int* __restrict__ offs,
    const int* __restrict__ perm, float* __restrict__ aout)
{
    const int e = blockIdx.z;
    const int off = offs[e];
    const int Ne = offs[e+1] - off;
    const int row0 = blockIdx.y * 64;
    if (row0 >= Ne) return;
    const int col0 = blockIdx.x * 64;
    const int tid = threadIdx.x, tx = tid & 15, ty = tid >> 4;
    __shared__ int toks[64];
    __shared__ __align__(16) float As[16][68], B1s[16][68], B2s[16][68];
    if (tid < 64) toks[tid] = (row0 + tid < Ne) ? perm[off + row0 + tid] : -1;
    __syncthreads();
    const int am = tid >> 2, ak = (tid & 3) * 4;
    const int bk = tid >> 4, bn = (tid & 15) * 4;
    const float* W = fcw + (size_t)e * D_ * F2_;
    const int tokA = toks[am];
    float c1[4][4] = {}, c2a[4][4] = {};
    for (int k0 = 0; k0 < D_; k0 += 16) {
        float4 av = make_float4(0.f, 0.f, 0.f, 0.f);
        if (tokA >= 0) av = *(const float4*)(h2 + (size_t)tokA*D_ + k0 + ak);
        float4 b1 = *(const float4*)(W + (size_t)(k0+bk)*F2_ + col0 + bn);
        float4 b2 = *(const float4*)(W + (size_t)(k0+bk)*F2_ + F_ + col0 + bn);
        As[ak+0][am]=av.x; As[ak+1][am]=av.y; As[ak+2][am]=av.z; As[ak+3][am]=av.w;
        *(float4*)&B1s[bk][bn] = b1;
        *(float4*)&B2s[bk][bn] = b2;
        __syncthreads();
        #pragma unroll
        for (int kk = 0; kk < 16; kk++) {
            float4 a4 = *(const float4*)&As[kk][ty*4];
            float4 p4 = *(const float4*)&B1s[kk][tx*4];
            float4 q4 = *(const float4*)&B2s[kk][tx*4];
            FMA16(c1, a4, p4)
            FMA16(c2a, a4, q4)
        }
        __syncthreads();
    }
    #pragma unroll
    for (int i = 0; i < 4; i++) {
        int tok = toks[ty*4 + i];
        if (tok < 0) continue;
        #pragma unroll
        for (int j = 0; j < 4; j++) {
            int c = col0 + tx*4 + j;
            float v1 = c1[i][j]  + fcb[(size_t)e*F2_ + c];
            float v2 = c2a[i][j] + fcb[(size_t)e*F2_ + F_ + c];
            float g = v2 * 0.5f * (1.0f + erff(v2 * 0.70710678118654752f));
            aout[(size_t)tok*F_ + c] = v1 * g;
        }
    }
}

// -------------------- grouped MoE out GEMM + scatter (resid + gate scale) --------------------
__global__ __launch_bounds__(256) void moe_out_kernel(
    const float* __restrict__ abuf, const float* __restrict__ ew,
    const float* __restrict__ eb, const int* __restrict__ offs,
    const int* __restrict__ perm, const float* __restrict__ gw,
    const float* __restrict__ x2, float* __restrict__ out)
{
    const int e = blockIdx.z;
    const int off = offs[e];
    const int Ne = offs[e+1] - off;
    const int row0 = blockIdx.y * 64;
    if (row0 >= Ne) return;
    const int col0 = blockIdx.x * 64;
    const int tid = threadIdx.x, tx = tid & 15, ty = tid >> 4;
    __shared__ int toks[64];
    __shared__ __align__(16) float As[16][68], Bs[16][68];
    if (tid < 64) toks[tid] = (row0 + tid < Ne) ? perm[off + row0 + tid] : -1;
    __syncthreads();
    const int am = tid >> 2, ak = (tid & 3) * 4;
    const int bk = tid >> 4, bn = (tid & 15) * 4;
    const float* W = ew + (size_t)e * F_ * D_;
    const int tokA = toks[am];
    float acc[4][4] = {};
    for (int k0 = 0; k0 < F_; k0 += 16) {
        float4 av = make_float4(0.f, 0.f, 0.f, 0.f);
        if (tokA >= 0) av = *(const float4*)(abuf + (size_t)tokA*F_ + k0 + ak);
        float4 bv = *(const float4*)(W + (size_t)(k0+bk)*D_ + col0 + bn);
        As[ak+0][am]=av.x; As[ak+1][am]=av.y; As[ak+2][am]=av.z; As[ak+3][am]=av.w;
        *(float4*)&Bs[bk][bn] = bv;
        __syncthreads();
        #pragma unroll
        for (int kk = 0; kk < 16; kk++) {
            float4 a4 = *(const float4*)&As[kk][ty*4];
            float4 b4 = *(const float4*)&Bs[kk][tx*4];
            FMA16(acc, a4, b4)
        }
        __syncthreads();
    }
    #pragma unroll
    for (int i = 0; i < 4; i++) {
        int tok = toks[ty*4 + i];
        if (tok < 0) continue;
        float g = gw[tok];
        #pragma unroll
        for (int j = 0; j < 4; j++) {
            int c = col0 + tx*4 + j;
            out[(size_t)tok*D_ + c] = x2[(size_t)tok*D_ + c]
                                    + g * (acc[i][j] + eb[(size_t)e*D_ + c]);
        }
    }
}

// -------------------- MoE aux loss --------------------
__global__ void loss_kernel(const int* __restrict__ gi,
                            const float* __restrict__ gw, float* __restrict__ out)
{
    __shared__ float ss[E_], sc[E_];
    const int tid = threadIdx.x;
    if (tid < E_) { ss[tid] = 0.f; sc[tid] = 0.f; }
    __syncthreads();
    for (int t = tid; t < T_; t += 256) {
        int e = gi[t];
        atomicAdd(&ss[e], gw[t]);
        atomicAdd(&sc[e], 1.0f);
    }
    __syncthreads();
    if (tid == 0) {
        float loss = 0.f;
        for (int e = 0; e < E_; e++) {
            float u = ss[e] / (sc[e] + 1e-8f);
            float d = u - 0.125f;
            loss += d * d;
        }
        out[(size_t)T_ * D_] = loss;
    }
}

extern "C" void kernel_launch(void* const* d_in, const int* in_sizes, int n_in,
                              void* d_out, int out_size, void* d_ws, size_t ws_size,
                              hipStream_t stream)
{
    const float* x     = (const float*)d_in[0];
    const int*   ids   = (const int*)d_in[1];
    const float* ln1w  = (const float*)d_in[2];
    const float* ln1b  = (const float*)d_in[3];
    const float* qkvw  = (const float*)d_in[4];
    const float* qkvb  = (const float*)d_in[5];
    const float* aow   = (const float*)d_in[6];
    const float* aob   = (const float*)d_in[7];
    const float* ln2w  = (const float*)d_in[8];
    const float* ln2b  = (const float*)d_in[9];
    const float* gatew = (const float*)d_in[10];
    const float* gateb = (const float*)d_in[11];
    const float* fcw   = (const float*)d_in[12];
    const float* fcb   = (const float*)d_in[13];
    const float* eoutw = (const float*)d_in[14];
    const float* eoutb = (const float*)d_in[15];
    float* out = (float*)d_out;
    float* ws  = (float*)d_ws;

    float* h    = ws + WS_H;
    float* qkv  = ws + WS_QKV;
    float* attn = ws + WS_ATTN;
    float* x2   = ws + WS_X2;
    float* h2   = ws + WS_H2;
    float* abuf = ws + WS_A;
    float* gw   = ws + WS_GW;
    int*   gi   = (int*)(ws + WS_GI);
    int*   offs = (int*)(ws + WS_OFFS);
    int*   perm = (int*)(ws + WS_PERM);

    // 1. LN1
    ln_kernel<<<T_, 256, 0, stream>>>(x, ln1w, ln1b, h);
    // 2. QKV projection
    gemm_nn<<<dim3(D3_/64, T_/64, 1), 256, 0, stream>>>(
        h, D_, 0, qkvw, D3_, 0, qkvb, nullptr, qkv, D3_, 0, T_, D3_, D_, 1.0f);
    // 3. RoPE in-place on q,k
    rope_kernel<<<(T_*H_*32)/256, 256, 0, stream>>>(qkv);
    // 4. fused attention
    attn_kernel<<<dim3(T_/4, H_), 256, 0, stream>>>(qkv, ids, attn);
    // 5. output projection + residual
    gemm_nn<<<dim3(D_/64, T_/64, 1), 256, 0, stream>>>(
        attn, D_, 0, aow, D_, 0, aob, x, x2, D_, 0, T_, D_, D_, 1.0f);
    // 6. LN2 + gate
    ln2_gate_kernel<<<T_, 256, 0, stream>>>(x2, ln2w, ln2b, gatew, gateb, h2, gi, gw);
    // 7. routing
    route_kernel<<<1, T_, 0, stream>>>(gi, offs, perm);
    // 8. expert fc + GLU
    moe_fc_kernel<<<dim3(F_/64, T_/64, E_), 256, 0, stream>>>(h2, fcw, fcb, offs, perm, abuf);
    // 9. expert out + scatter + residual
    moe_out_kernel<<<dim3(D_/64, T_/64, E_), 256, 0, stream>>>(abuf, eoutw, eoutb, offs, perm, gw, x2, out);
    // 10. aux loss
    loss_kernel<<<1, 256, 0, stream>>>(gi, gw, out);
}

// Round 2
// 959.331 us; speedup vs baseline: 1.4755x; 1.4755x over previous
//
#include <hip/hip_runtime.h>
#include <float.h>
#include <math.h>
#include <stdint.h>

#define T_ 1024
#define D_ 1024
#define H_ 16
#define HD_ 64
#define E_ 8
#define F_ 2560
#define D3_ 3072
#define F2_ 5120

// ---- workspace layout (float offsets) ----
#define WS_H    0u         // 1M   LN1 out; later reused as SACC (split-K accum)
#define WS_QKV  1048576u   // 3M   qkv (T,3D)
#define WS_ATTN 4194304u   // 1M   attention out (T,D)
#define WS_X2   5242880u   // 1M   x + attn proj (T,D)
#define WS_H2   6291456u   // 1M   LN2 out
#define WS_A    7340032u   // 2.62M gated activation (T,F)
#define WS_GW   9961472u
#define WS_GI   9962496u
#define WS_OFFS 9963520u
#define WS_PERM 9963536u

typedef short short8 __attribute__((ext_vector_type(8)));
typedef __bf16 bf16x8 __attribute__((ext_vector_type(8)));
typedef float floatx4 __attribute__((ext_vector_type(4)));

union FragU { short8 s; bf16x8 b; };

__device__ __forceinline__ short f2bf(float f) {
    union { float f; uint32_t u; } a; a.f = f;
    uint32_t r = a.u + 0x7fffu + ((a.u >> 16) & 1u);
    return (short)(r >> 16);
}

// ===================== MFMA GEMM cores =====================
// Tile: BM=128, BN=64, BK=32. 256 threads = 4 waves (2x2), wave tile 64x32.
// As: [kc:4][m:128][j:8] bf16 (8 KB).  Bs: [n:64][pad-40] bf16 (5 KB).
// A-frag(i): As[quad][wm*64+i*16+(lane&15)][0..7]      (ds_read_b128)
// B-frag(j): Bs[wn*32+j*16+(lane&15)][quad*8 .. +7]    (ds_read_b128)
// C/D: col=lane&15, row=(lane>>4)*4+reg  [m89-verified]

#define GEMM_IDS \
    const int tid  = threadIdx.x;                 \
    const int a_m  = tid >> 1;                    \
    const int a_kh = (tid & 1) * 16;              \
    const int b_n  = tid >> 2;                    \
    const int b_kc = tid & 3;                     \
    const int lane = tid & 63, wave = tid >> 6;   \
    const int wm = wave & 1,  wn = wave >> 1;     \
    const int quad = lane >> 4, lm = lane & 15;

__device__ __forceinline__ void cvt16(const float4& a0, const float4& a1,
                                      const float4& a2, const float4& a3,
                                      short8& c0, short8& c1) {
    c0[0]=f2bf(a0.x); c0[1]=f2bf(a0.y); c0[2]=f2bf(a0.z); c0[3]=f2bf(a0.w);
    c0[4]=f2bf(a1.x); c0[5]=f2bf(a1.y); c0[6]=f2bf(a1.z); c0[7]=f2bf(a1.w);
    c1[0]=f2bf(a2.x); c1[1]=f2bf(a2.y); c1[2]=f2bf(a2.z); c1[3]=f2bf(a2.w);
    c1[4]=f2bf(a3.x); c1[5]=f2bf(a3.y); c1[6]=f2bf(a3.z); c1[7]=f2bf(a3.w);
}

// ---- full GEMM: C = A@B + bias (qkv projection) ----
__global__ __launch_bounds__(256) void gemm_mfma_full(
    const float* __restrict__ A, int lda,
    const float* __restrict__ B, int ldb,
    const float* __restrict__ bias,
    float* __restrict__ C, int ldc, int K)
{
    __shared__ __align__(16) short As[4*128*8];
    __shared__ __align__(16) short Bs[64*40];
    const int row0 = blockIdx.y * 128, col0 = blockIdx.x * 64;
    GEMM_IDS
    floatx4 acc[4][2];
    #pragma unroll
    for (int i=0;i<4;i++)
        #pragma unroll
        for (int j=0;j<2;j++) acc[i][j] = (floatx4){0.f,0.f,0.f,0.f};

    const float* apx = A + (size_t)(row0 + a_m) * lda + a_kh;
    const float* bpx = B + (size_t)(b_kc*8) * ldb + col0 + b_n;
    const int kcA = (tid & 1) * 2;

    for (int k0 = 0; k0 < K; k0 += 32) {
        float4 a0 = *(const float4*)(apx + k0);
        float4 a1 = *(const float4*)(apx + k0 + 4);
        float4 a2 = *(const float4*)(apx + k0 + 8);
        float4 a3 = *(const float4*)(apx + k0 + 12);
        float bvv[8];
        const float* bp = bpx + (size_t)k0 * ldb;
        #pragma unroll
        for (int j=0;j<8;j++) bvv[j] = bp[(size_t)j*ldb];
        __syncthreads();
        short8 c0, c1, cb;
        cvt16(a0,a1,a2,a3,c0,c1);
        #pragma unroll
        for (int j=0;j<8;j++) cb[j] = f2bf(bvv[j]);
        *(short8*)&As[((kcA  )*128 + a_m)*8] = c0;
        *(short8*)&As[((kcA+1)*128 + a_m)*8] = c1;
        *(short8*)&Bs[b_n*40 + b_kc*8] = cb;
        __syncthreads();
        FragU fa[4], fb[2];
        #pragma unroll
        for (int i=0;i<4;i++) fa[i].s = *(short8*)&As[(quad*128 + wm*64 + i*16 + lm)*8];
        #pragma unroll
        for (int j=0;j<2;j++) fb[j].s = *(short8*)&Bs[(wn*32 + j*16 + lm)*40 + quad*8];
        #pragma unroll
        for (int i=0;i<4;i++)
            #pragma unroll
            for (int j=0;j<2;j++)
                acc[i][j] = __builtin_amdgcn_mfma_f32_16x16x32_bf16(fa[i].b, fb[j].b, acc[i][j], 0,0,0);
    }
    #pragma unroll
    for (int i=0;i<4;i++)
        #pragma unroll
        for (int j=0;j<2;j++) {
            int col = col0 + wn*32 + j*16 + lm;
            float bb = bias ? bias[col] : 0.f;
            #pragma unroll
            for (int r=0;r<4;r++) {
                int row = row0 + wm*64 + i*16 + quad*4 + r;
                C[(size_t)row*ldc + col] = acc[i][j][r] + bb;
            }
        }
}

// ---- split-K accumulating GEMM (optionally token-routed): Cacc += A@B ----
// blockIdx.z: e = z>>1, sk = z&1 (K halves). For non-routed pass offs=nullptr.
__global__ __launch_bounds__(256) void gemm_mfma_acc(
    const float* __restrict__ A, int lda,
    const float* __restrict__ B, int ldb, long sB,
    const int* __restrict__ offs, const int* __restrict__ perm,
    float* __restrict__ Cacc, int ldc, int K)
{
    const int e  = blockIdx.z >> 1;
    const int sk = blockIdx.z & 1;
    int off = 0, Ne = T_;
    if (offs) { off = offs[e]; Ne = offs[e+1] - off; }
    const int row0 = blockIdx.y * 128;
    if (row0 >= Ne) return;
    const int col0 = blockIdx.x * 64;
    B += (long)e * sB;

    __shared__ __align__(16) short As[4*128*8];
    __shared__ __align__(16) short Bs[64*40];
    __shared__ int toks[128];
    GEMM_IDS
    if (tid < 128) {
        int r = row0 + tid;
        toks[tid] = offs ? ((r < Ne) ? perm[off + r] : -1) : r;
    }
    __syncthreads();

    floatx4 acc[4][2];
    #pragma unroll
    for (int i=0;i<4;i++)
        #pragma unroll
        for (int j=0;j<2;j++) acc[i][j] = (floatx4){0.f,0.f,0.f,0.f};

    const int tokA = toks[a_m];
    const float* apx = (tokA >= 0) ? (A + (size_t)tokA * lda + a_kh) : nullptr;
    const float* bpx = B + (size_t)(b_kc*8) * ldb + col0 + b_n;
    const int kcA = (tid & 1) * 2;
    const int koff = sk * (K >> 1), kend = koff + (K >> 1);

    for (int k0 = koff; k0 < kend; k0 += 32) {
        float4 a0 = make_float4(0,0,0,0), a1 = a0, a2 = a0, a3 = a0;
        if (apx) {
            a0 = *(const float4*)(apx + k0);
            a1 = *(const float4*)(apx + k0 + 4);
            a2 = *(const float4*)(apx + k0 + 8);
            a3 = *(const float4*)(apx + k0 + 12);
        }
        float bvv[8];
        const float* bp = bpx + (size_t)k0 * ldb;
        #pragma unroll
        for (int j=0;j<8;j++) bvv[j] = bp[(size_t)j*ldb];
        __syncthreads();
        short8 c0, c1, cb;
        cvt16(a0,a1,a2,a3,c0,c1);
        #pragma unroll
        for (int j=0;j<8;j++) cb[j] = f2bf(bvv[j]);
        *(short8*)&As[((kcA  )*128 + a_m)*8] = c0;
        *(short8*)&As[((kcA+1)*128 + a_m)*8] = c1;
        *(short8*)&Bs[b_n*40 + b_kc*8] = cb;
        __syncthreads();
        FragU fa[4], fb[2];
        #pragma unroll
        for (int i=0;i<4;i++) fa[i].s = *(short8*)&As[(quad*128 + wm*64 + i*16 + lm)*8];
        #pragma unroll
        for (int j=0;j<2;j++) fb[j].s = *(short8*)&Bs[(wn*32 + j*16 + lm)*40 + quad*8];
        #pragma unroll
        for (int i=0;i<4;i++)
            #pragma unroll
            for (int j=0;j<2;j++)
                acc[i][j] = __builtin_amdgcn_mfma_f32_16x16x32_bf16(fa[i].b, fb[j].b, acc[i][j], 0,0,0);
    }
    #pragma unroll
    for (int i=0;i<4;i++)
        #pragma unroll
        for (int j=0;j<2;j++) {
            int col = col0 + wn*32 + j*16 + lm;
            #pragma unroll
            for (int r=0;r<4;r++) {
                int tk = toks[wm*64 + i*16 + quad*4 + r];
                if (tk >= 0) atomicAdd(&Cacc[(size_t)tk*ldc + col], acc[i][j][r]);
            }
        }
}

// ---- MoE fc GEMM, dual-B (GLU halves) + exact-gelu epilogue ----
__global__ __launch_bounds__(256) void moe_fc_mfma(
    const float* __restrict__ h2, const float* __restrict__ fcw,
    const float* __restrict__ fcb, const int* __restrict__ offs,
    const int* __restrict__ perm, float* __restrict__ aout)
{
    const int e = blockIdx.z;
    const int off = offs[e];
    const int Ne = offs[e+1] - off;
    const int row0 = blockIdx.y * 128;
    if (row0 >= Ne) return;
    const int col0 = blockIdx.x * 64;

    __shared__ __align__(16) short As[4*128*8];
    __shared__ __align__(16) short B1s[64*40];
    __shared__ __align__(16) short B2s[64*40];
    __shared__ int toks[128];
    GEMM_IDS
    if (tid < 128) {
        int r = row0 + tid;
        toks[tid] = (r < Ne) ? perm[off + r] : -1;
    }
    __syncthreads();

    floatx4 acc1[4][2], acc2[4][2];
    #pragma unroll
    for (int i=0;i<4;i++)
        #pragma unroll
        for (int j=0;j<2;j++) {
            acc1[i][j] = (floatx4){0.f,0.f,0.f,0.f};
            acc2[i][j] = (floatx4){0.f,0.f,0.f,0.f};
        }

    const float* W = fcw + (size_t)e * D_ * F2_;
    const int tokA = toks[a_m];
    const float* apx = (tokA >= 0) ? (h2 + (size_t)tokA * D_ + a_kh) : nullptr;
    const float* bpx = W + (size_t)(b_kc*8) * F2_ + col0 + b_n;
    const int kcA = (tid & 1) * 2;

    for (int k0 = 0; k0 < D_; k0 += 32) {
        float4 a0 = make_float4(0,0,0,0), a1 = a0, a2 = a0, a3 = a0;
        if (apx) {
            a0 = *(const float4*)(apx + k0);
            a1 = *(const float4*)(apx + k0 + 4);
            a2 = *(const float4*)(apx + k0 + 8);
            a3 = *(const float4*)(apx + k0 + 12);
        }
        float bv1[8], bv2[8];
        const float* bp = bpx + (size_t)k0 * F2_;
        #pragma unroll
        for (int j=0;j<8;j++) { bv1[j] = bp[(size_t)j*F2_]; bv2[j] = bp[(size_t)j*F2_ + F_]; }
        __syncthreads();
        short8 c0, c1, cb1, cb2;
        cvt16(a0,a1,a2,a3,c0,c1);
        #pragma unroll
        for (int j=0;j<8;j++) { cb1[j] = f2bf(bv1[j]); cb2[j] = f2bf(bv2[j]); }
        *(short8*)&As[((kcA  )*128 + a_m)*8] = c0;
        *(short8*)&As[((kcA+1)*128 + a_m)*8] = c1;
        *(short8*)&B1s[b_n*40 + b_kc*8] = cb1;
        *(short8*)&B2s[b_n*40 + b_kc*8] = cb2;
        __syncthreads();
        FragU fa[4], fb1[2], fb2[2];
        #pragma unroll
        for (int i=0;i<4;i++) fa[i].s = *(short8*)&As[(quad*128 + wm*64 + i*16 + lm)*8];
        #pragma unroll
        for (int j=0;j<2;j++) {
            fb1[j].s = *(short8*)&B1s[(wn*32 + j*16 + lm)*40 + quad*8];
            fb2[j].s = *(short8*)&B2s[(wn*32 + j*16 + lm)*40 + quad*8];
        }
        #pragma unroll
        for (int i=0;i<4;i++)
            #pragma unroll
            for (int j=0;j<2;j++) {
                acc1[i][j] = __builtin_amdgcn_mfma_f32_16x16x32_bf16(fa[i].b, fb1[j].b, acc1[i][j], 0,0,0);
                acc2[i][j] = __builtin_amdgcn_mfma_f32_16x16x32_bf16(fa[i].b, fb2[j].b, acc2[i][j], 0,0,0);
            }
    }
    #pragma unroll
    for (int i=0;i<4;i++)
        #pragma unroll
        for (int j=0;j<2;j++) {
            int col = col0 + wn*32 + j*16 + lm;
            float b1 = fcb[(size_t)e*F2_ + col];
            float b2 = fcb[(size_t)e*F2_ + F_ + col];
            #pragma unroll
            for (int r=0;r<4;r++) {
                int tk = toks[wm*64 + i*16 + quad*4 + r];
                if (tk < 0) continue;
                float v1 = acc1[i][j][r] + b1;
                float v2 = acc2[i][j][r] + b2;
                float g = v2 * 0.5f * (1.0f + erff(v2 * 0.70710678118654752f));
                aout[(size_t)tk*F_ + col] = v1 * g;
            }
        }
}

// ===================== epilogues =====================
__global__ __launch_bounds__(256) void ep_attn(
    const float* __restrict__ x, const float* __restrict__ sacc,
    const float* __restrict__ aob, float* __restrict__ x2)
{
    int row = blockIdx.x, tid = threadIdx.x;
    float4 xv = ((const float4*)(x + (size_t)row*D_))[tid];
    float4 sv = ((const float4*)(sacc + (size_t)row*D_))[tid];
    float4 bv = ((const float4*)aob)[tid];
    float4 o;
    o.x = xv.x + sv.x + bv.x; o.y = xv.y + sv.y + bv.y;
    o.z = xv.z + sv.z + bv.z; o.w = xv.w + sv.w + bv.w;
    ((float4*)(x2 + (size_t)row*D_))[tid] = o;
}

__global__ __launch_bounds__(256) void ep_moe(
    const float* __restrict__ x2, const float* __restrict__ sacc,
    const float* __restrict__ eob, const float* __restrict__ gw,
    const int* __restrict__ gi, float* __restrict__ out)
{
    int row = blockIdx.x, tid = threadIdx.x;
    float g = gw[row];
    int e = gi[row];
    float4 xv = ((const float4*)(x2 + (size_t)row*D_))[tid];
    float4 sv = ((const float4*)(sacc + (size_t)row*D_))[tid];
    float4 bv = ((const float4*)(eob + (size_t)e*D_))[tid];
    float4 o;
    o.x = xv.x + g*(sv.x + bv.x); o.y = xv.y + g*(sv.y + bv.y);
    o.z = xv.z + g*(sv.z + bv.z); o.w = xv.w + g*(sv.w + bv.w);
    ((float4*)(out + (size_t)row*D_))[tid] = o;
}

// ===================== unchanged round-1 kernels =====================
__global__ __launch_bounds__(256) void ln_kernel(
    const float* __restrict__ x, const float* __restrict__ w,
    const float* __restrict__ b, float* __restrict__ out)
{
    const int row = blockIdx.x, tid = threadIdx.x;
    const int lane = tid & 63, wave = tid >> 6;
    float4 v = ((const float4*)(x + (size_t)row * D_))[tid];
    float s  = v.x + v.y + v.z + v.w;
    float sq = v.x*v.x + v.y*v.y + v.z*v.z + v.w*v.w;
    #pragma unroll
    for (int off = 32; off; off >>= 1) {
        s  += __shfl_down(s, off);
        sq += __shfl_down(sq, off);
    }
    __shared__ float rs[4], rq[4], mv[2];
    if (lane == 0) { rs[wave] = s; rq[wave] = sq; }
    __syncthreads();
    if (tid == 0) {
        float ts = rs[0]+rs[1]+rs[2]+rs[3];
        float tq = rq[0]+rq[1]+rq[2]+rq[3];
        float mean = ts * (1.0f / D_);
        float var  = tq * (1.0f / D_) - mean*mean;
        mv[0] = mean; mv[1] = rsqrtf(var + 1e-5f);
    }
    __syncthreads();
    float mean = mv[0], rstd = mv[1];
    float4 wv = ((const float4*)w)[tid];
    float4 bv = ((const float4*)b)[tid];
    float4 o;
    o.x = (v.x-mean)*rstd*wv.x + bv.x;
    o.y = (v.y-mean)*rstd*wv.y + bv.y;
    o.z = (v.z-mean)*rstd*wv.z + bv.z;
    o.w = (v.w-mean)*rstd*wv.w + bv.w;
    ((float4*)(out + (size_t)row * D_))[tid] = o;
}

__global__ __launch_bounds__(256) void rope_kernel(float* __restrict__ qkv)
{
    int gid = blockIdx.x * 256 + threadIdx.x;
    int t = gid >> 9;
    int r = gid & 511;
    int h = r >> 5;
    int d = r & 31;
    float inv = powf(10000.0f, -(float)d * (1.0f/32.0f));
    float fr = (float)t * inv;
    float s, c;
    sincosf(fr, &s, &c);
    float* base = qkv + (size_t)t*D3_ + h*HD_ + d;
    float q1 = base[0], q2 = base[32];
    base[0]  = q1*c - q2*s;
    base[32] = q1*s + q2*c;
    float* kb = base + D_;
    float k1 = kb[0], k2 = kb[32];
    kb[0]  = k1*c - k2*s;
    kb[32] = k1*s + k2*c;
}

__global__ __launch_bounds__(256) void attn_kernel(
    const float* __restrict__ qkv, const int* __restrict__ ids,
    float* __restrict__ attnout)
{
    const int h = blockIdx.y;
    const int q0 = blockIdx.x * 4;
    const int tid = threadIdx.x;
    const int lane = tid & 63, wave = tid >> 6;

    __shared__ __align__(16) float qv[4][64];
    __shared__ float pp[4][1024];
    __shared__ float red[4][4];
    __shared__ float bcm[4], bcs[4];
    __shared__ float pv[4][4][64];

    {
        int qi = tid >> 6, d = tid & 63;
        qv[qi][d] = qkv[(size_t)(q0+qi)*D3_ + h*HD_ + d];
    }
    int kmax[4];
    int kall = 0;
    #pragma unroll
    for (int qi = 0; qi < 4; qi++) {
        int id = ids[q0+qi];
        bool glob = (id >= 2 && id <= 7);
        kmax[qi] = glob ? T_ : (q0 + qi + 1);
        kall = max(kall, kmax[qi]);
    }
    __syncthreads();

    float mx[4] = {-FLT_MAX, -FLT_MAX, -FLT_MAX, -FLT_MAX};
    #pragma unroll
    for (int i = 0; i < 4; i++) {
        int k = tid + i*256;
        float dot[4] = {0.f, 0.f, 0.f, 0.f};
        if (k < kall) {
            const float* kr = qkv + (size_t)k*D3_ + D_ + h*HD_;
            #pragma unroll
            for (int d = 0; d < 64; d += 4) {
                float4 kv4 = *(const float4*)(kr + d);
                #pragma unroll
                for (int qi = 0; qi < 4; qi++) {
                    float4 q4 = *(const float4*)&qv[qi][d];
                    dot[qi] += q4.x*kv4.x + q4.y*kv4.y + q4.z*kv4.z + q4.w*kv4.w;
                }
            }
        }
        #pragma unroll
        for (int qi = 0; qi < 4; qi++) {
            float l = (k < kmax[qi]) ? dot[qi]*0.125f : -FLT_MAX;
            pp[qi][k] = l;
            mx[qi] = fmaxf(mx[qi], l);
        }
    }
    #pragma unroll
    for (int off = 32; off; off >>= 1)
        #pragma unroll
        for (int qi = 0; qi < 4; qi++)
            mx[qi] = fmaxf(mx[qi], __shfl_down(mx[qi], off));
    if (lane == 0)
        for (int qi = 0; qi < 4; qi++) red[qi][wave] = mx[qi];
    __syncthreads();
    if (tid < 4)
        bcm[tid] = fmaxf(fmaxf(red[tid][0], red[tid][1]), fmaxf(red[tid][2], red[tid][3]));
    __syncthreads();

    float m4[4] = {bcm[0], bcm[1], bcm[2], bcm[3]};
    float sm[4] = {0.f, 0.f, 0.f, 0.f};
    #pragma unroll
    for (int i = 0; i < 4; i++) {
        int k = tid + i*256;
        #pragma unroll
        for (int qi = 0; qi < 4; qi++) {
            float e = expf(pp[qi][k] - m4[qi]);
            pp[qi][k] = e;
            sm[qi] += e;
        }
    }
    #pragma unroll
    for (int off = 32; off; off >>= 1)
        #pragma unroll
        for (int qi = 0; qi < 4; qi++)
            sm[qi] += __shfl_down(sm[qi], off);
    if (lane == 0)
        for (int qi = 0; qi < 4; qi++) red[qi][wave] = sm[qi];
    __syncthreads();
    if (tid < 4)
        bcs[tid] = red[tid][0] + red[tid][1] + red[tid][2] + red[tid][3];
    __syncthreads();

    const int tx = tid & 63, ty = tid >> 6;
    float acc[4] = {0.f, 0.f, 0.f, 0.f};
    int kend = min(kall, (ty+1)*256);
    for (int k = ty*256; k < kend; k++) {
        float vv = qkv[(size_t)k*D3_ + 2*D_ + h*HD_ + tx];
        #pragma unroll
        for (int qi = 0; qi < 4; qi++) acc[qi] += pp[qi][k] * vv;
    }
    #pragma unroll
    for (int qi = 0; qi < 4; qi++) pv[ty][qi][tx] = acc[qi];
    __syncthreads();
    if (ty == 0) {
        #pragma unroll
        for (int qi = 0; qi < 4; qi++) {
            float o = (pv[0][qi][tx] + pv[1][qi][tx] + pv[2][qi][tx] + pv[3][qi][tx]) / bcs[qi];
            attnout[(size_t)(q0+qi)*D_ + h*HD_ + tx] = o;
        }
    }
}

__global__ __launch_bounds__(256) void ln2_gate_kernel(
    const float* __restrict__ x2, const float* __restrict__ w,
    const float* __restrict__ b, const float* __restrict__ gwm,
    const float* __restrict__ gbv, float* __restrict__ h2,
    int* __restrict__ gi, float* __restrict__ gw)
{
    const int row = blockIdx.x, tid = threadIdx.x;
    const int lane = tid & 63, wave = tid >> 6;
    float4 v = ((const float4*)(x2 + (size_t)row * D_))[tid];
    float s  = v.x + v.y + v.z + v.w;
    float sq = v.x*v.x + v.y*v.y + v.z*v.z + v.w*v.w;
    #pragma unroll
    for (int off = 32; off; off >>= 1) {
        s  += __shfl_down(s, off);
        sq += __shfl_down(sq, off);
    }
    __shared__ float rs[4], rq[4], mv[2];
    if (lane == 0) { rs[wave] = s; rq[wave] = sq; }
    __syncthreads();
    if (tid == 0) {
        float ts = rs[0]+rs[1]+rs[2]+rs[3];
        float tq = rq[0]+rq[1]+rq[2]+rq[3];
        float mean = ts * (1.0f / D_);
        float var  = tq * (1.0f / D_) - mean*mean;
        mv[0] = mean; mv[1] = rsqrtf(var + 1e-5f);
    }
    __syncthreads();
    float mean = mv[0], rstd = mv[1];
    float4 wv = ((const float4*)w)[tid];
    float4 bv = ((const float4*)b)[tid];
    float hv[4];
    hv[0] = (v.x-mean)*rstd*wv.x + bv.x;
    hv[1] = (v.y-mean)*rstd*wv.y + bv.y;
    hv[2] = (v.z-mean)*rstd*wv.z + bv.z;
    hv[3] = (v.w-mean)*rstd*wv.w + bv.w;
    float4 o; o.x=hv[0]; o.y=hv[1]; o.z=hv[2]; o.w=hv[3];
    ((float4*)(h2 + (size_t)row * D_))[tid] = o;

    float acc[E_] = {};
    int c = tid * 4;
    #pragma unroll
    for (int j = 0; j < 4; j++) {
        const float* gr = gwm + (size_t)(c+j) * E_;
        #pragma unroll
        for (int e = 0; e < E_; e++) acc[e] += hv[j] * gr[e];
    }
    #pragma unroll
    for (int off = 32; off; off >>= 1)
        #pragma unroll
        for (int e = 0; e < E_; e++) acc[e] += __shfl_down(acc[e], off);
    __shared__ float gred[4][E_];
    if (lane == 0)
        for (int e = 0; e < E_; e++) gred[wave][e] = acc[e];
    __syncthreads();
    if (tid == 0) {
        float lg[E_];
        float mxl = -FLT_MAX; int mi = 0;
        for (int e = 0; e < E_; e++)
            lg[e] = gred[0][e]+gred[1][e]+gred[2][e]+gred[3][e] + gbv[e];
        for (int e = 0; e < E_; e++)
            if (lg[e] > mxl) { mxl = lg[e]; mi = e; }
        float ssum = 0.f;
        for (int e = 0; e < E_; e++) ssum += expf(lg[e] - mxl);
        gi[row] = mi;
        gw[row] = 1.0f / ssum;
    }
}

__global__ void route_kernel(const int* __restrict__ gi,
                             int* __restrict__ offs, int* __restrict__ perm)
{
    __shared__ int cnt[E_], c2[E_], off[E_+1];
    const int tid = threadIdx.x;
    if (tid < E_) { cnt[tid] = 0; c2[tid] = 0; }
    __syncthreads();
    int e = gi[tid];
    atomicAdd(&cnt[e], 1);
    __syncthreads();
    if (tid == 0) {
        off[0] = 0;
        for (int i = 0; i < E_; i++) off[i+1] = off[i] + cnt[i];
        for (int i = 0; i <= E_; i++) offs[i] = off[i];
    }
    __syncthreads();
    int r = atomicAdd(&c2[e], 1);
    perm[off[e] + r] = tid;
}

__global__ void loss_kernel(const int* __restrict__ gi,
                            const float* __restrict__ gw, float* __restrict__ out)
{
    __shared__ float ss[E_], sc[E_];
    const int tid = threadIdx.x;
    if (tid < E_) { ss[tid] = 0.f; sc[tid] = 0.f; }
    __syncthreads();
    for (int t = tid; t < T_; t += 256) {
        int e = gi[t];
        atomicAdd(&ss[e], gw[t]);
        atomicAdd(&sc[e], 1.0f);
    }
    __syncthreads();
    if (tid == 0) {
        float loss = 0.f;
        for (int e = 0; e < E_; e++) {
            float u = ss[e] / (sc[e] + 1e-8f);
            float d = u - 0.125f;
            loss += d * d;
        }
        out[(size_t)T_ * D_] = loss;
    }
}

extern "C" void kernel_launch(void* const* d_in, const int* in_sizes, int n_in,
                              void* d_out, int out_size, void* d_ws, size_t ws_size,
                              hipStream_t stream)
{
    const float* x     = (const float*)d_in[0];
    const int*   ids   = (const int*)d_in[1];
    const float* ln1w  = (const float*)d_in[2];
    const float* ln1b  = (const float*)d_in[3];
    const float* qkvw  = (const float*)d_in[4];
    const float* qkvb  = (const float*)d_in[5];
    const float* aow   = (const float*)d_in[6];
    const float* aob   = (const float*)d_in[7];
    const float* ln2w  = (const float*)d_in[8];
    const float* ln2b  = (const float*)d_in[9];
    const float* gatew = (const float*)d_in[10];
    const float* gateb = (const float*)d_in[11];
    const float* fcw   = (const float*)d_in[12];
    const float* fcb   = (const float*)d_in[13];
    const float* eoutw = (const float*)d_in[14];
    const float* eoutb = (const float*)d_in[15];
    float* out = (float*)d_out;
    float* ws  = (float*)d_ws;

    float* h    = ws + WS_H;      // reused as SACC after qkv GEMM
    float* sacc = ws + WS_H;
    float* qkv  = ws + WS_QKV;
    float* attn = ws + WS_ATTN;
    float* x2   = ws + WS_X2;
    float* h2   = ws + WS_H2;
    float* abuf = ws + WS_A;
    float* gw   = ws + WS_GW;
    int*   gi   = (int*)(ws + WS_GI);
    int*   offs = (int*)(ws + WS_OFFS);
    int*   perm = (int*)(ws + WS_PERM);

    // 1. LN1
    ln_kernel<<<T_, 256, 0, stream>>>(x, ln1w, ln1b, h);
    // 2. QKV projection (MFMA)
    gemm_mfma_full<<<dim3(D3_/64, T_/128), 256, 0, stream>>>(
        h, D_, qkvw, D3_, qkvb, qkv, D3_, D_);
    // 3. RoPE
    rope_kernel<<<(T_*H_*32)/256, 256, 0, stream>>>(qkv);
    // 4. attention (fp32, unchanged)
    attn_kernel<<<dim3(T_/4, H_), 256, 0, stream>>>(qkv, ids, attn);
    // 5. zero split-K accumulator (h is dead now)
    hipMemsetAsync(sacc, 0, (size_t)T_*D_*sizeof(float), stream);
    // 6. attn output projection (MFMA, split-K=2, accumulate)
    gemm_mfma_acc<<<dim3(D_/64, T_/128, 2), 256, 0, stream>>>(
        attn, D_, aow, D_, 0, nullptr, nullptr, sacc, D_, D_);
    // 7. residual + bias
    ep_attn<<<T_, 256, 0, stream>>>(x, sacc, aob, x2);
    // 8. LN2 + gate
    ln2_gate_kernel<<<T_, 256, 0, stream>>>(x2, ln2w, ln2b, gatew, gateb, h2, gi, gw);
    // 9. routing
    route_kernel<<<1, T_, 0, stream>>>(gi, offs, perm);
    // 10. expert fc + GLU (MFMA)
    moe_fc_mfma<<<dim3(F_/64, T_/128, E_), 256, 0, stream>>>(h2, fcw, fcb, offs, perm, abuf);
    // 11. re-zero accumulator
    hipMemsetAsync(sacc, 0, (size_t)T_*D_*sizeof(float), stream);
    // 12. expert out (MFMA, split-K=2, routed accumulate)
    gemm_mfma_acc<<<dim3(D_/64, T_/128, 2*E_), 256, 0, stream>>>(
        abuf, F_, eoutw, D_, (long)F_*D_, offs, perm, sacc, D_, F_);
    // 13. residual + gate scale + bias
    ep_moe<<<T_, 256, 0, stream>>>(x2, sacc, eoutb, gw, gi, out);
    // 14. aux loss
    loss_kernel<<<1, 256, 0, stream>>>(gi, gw, out);
}

// Round 3
// 688.021 us; speedup vs baseline: 2.0574x; 1.3943x over previous
//
#include <hip/hip_runtime.h>
#include <float.h>
#include <math.h>
#include <stdint.h>

#define T_ 1024
#define D_ 1024
#define H_ 16
#define HD_ 64
#define E_ 8
#define F_ 2560
#define D3_ 3072
#define F2_ 5120

// ---- workspace layout (float offsets) ----
#define WS_H    0u         // 1M   LN1 out; later reused as SACC (split-K accum)
#define WS_QKV  1048576u   // 3M   qkv (T,3D)
#define WS_ATTN 4194304u   // 1M   attention out (T,D)
#define WS_X2   5242880u   // 1M   x + attn proj (T,D)
#define WS_H2   6291456u   // 1M   LN2 out
#define WS_A    7340032u   // 2.62M gated activation (T,F)
#define WS_GW   9961472u
#define WS_GI   9962496u
#define WS_OFFS 9963520u
#define WS_PERM 9963536u

typedef short short8 __attribute__((ext_vector_type(8)));
typedef __bf16 bf16x8 __attribute__((ext_vector_type(8)));
typedef float floatx4 __attribute__((ext_vector_type(4)));

union FragU { short8 s; bf16x8 b; };

__device__ __forceinline__ short f2bf(float f) {
    union { float f; uint32_t u; } a; a.f = f;
    uint32_t r = a.u + 0x7fffu + ((a.u >> 16) & 1u);
    return (short)(r >> 16);
}

__device__ __forceinline__ void cvt16(const float4& a0, const float4& a1,
                                      const float4& a2, const float4& a3,
                                      short8& c0, short8& c1) {
    c0[0]=f2bf(a0.x); c0[1]=f2bf(a0.y); c0[2]=f2bf(a0.z); c0[3]=f2bf(a0.w);
    c0[4]=f2bf(a1.x); c0[5]=f2bf(a1.y); c0[6]=f2bf(a1.z); c0[7]=f2bf(a1.w);
    c1[0]=f2bf(a2.x); c1[1]=f2bf(a2.y); c1[2]=f2bf(a2.z); c1[3]=f2bf(a2.w);
    c1[4]=f2bf(a3.x); c1[5]=f2bf(a3.y); c1[6]=f2bf(a3.z); c1[7]=f2bf(a3.w);
}

// ===================== MFMA GEMM cores (round-2, unchanged) =====================
#define GEMM_IDS \
    const int tid  = threadIdx.x;                 \
    const int a_m  = tid >> 1;                    \
    const int a_kh = (tid & 1) * 16;              \
    const int b_n  = tid >> 2;                    \
    const int b_kc = tid & 3;                     \
    const int lane = tid & 63, wave = tid >> 6;   \
    const int wm = wave & 1,  wn = wave >> 1;     \
    const int quad = lane >> 4, lm = lane & 15;

__global__ __launch_bounds__(256) void gemm_mfma_full(
    const float* __restrict__ A, int lda,
    const float* __restrict__ B, int ldb,
    const float* __restrict__ bias,
    float* __restrict__ C, int ldc, int K)
{
    __shared__ __align__(16) short As[4*128*8];
    __shared__ __align__(16) short Bs[64*40];
    const int row0 = blockIdx.y * 128, col0 = blockIdx.x * 64;
    GEMM_IDS
    floatx4 acc[4][2];
    #pragma unroll
    for (int i=0;i<4;i++)
        #pragma unroll
        for (int j=0;j<2;j++) acc[i][j] = (floatx4){0.f,0.f,0.f,0.f};

    const float* apx = A + (size_t)(row0 + a_m) * lda + a_kh;
    const float* bpx = B + (size_t)(b_kc*8) * ldb + col0 + b_n;
    const int kcA = (tid & 1) * 2;

    for (int k0 = 0; k0 < K; k0 += 32) {
        float4 a0 = *(const float4*)(apx + k0);
        float4 a1 = *(const float4*)(apx + k0 + 4);
        float4 a2 = *(const float4*)(apx + k0 + 8);
        float4 a3 = *(const float4*)(apx + k0 + 12);
        float bvv[8];
        const float* bp = bpx + (size_t)k0 * ldb;
        #pragma unroll
        for (int j=0;j<8;j++) bvv[j] = bp[(size_t)j*ldb];
        __syncthreads();
        short8 c0, c1, cb;
        cvt16(a0,a1,a2,a3,c0,c1);
        #pragma unroll
        for (int j=0;j<8;j++) cb[j] = f2bf(bvv[j]);
        *(short8*)&As[((kcA  )*128 + a_m)*8] = c0;
        *(short8*)&As[((kcA+1)*128 + a_m)*8] = c1;
        *(short8*)&Bs[b_n*40 + b_kc*8] = cb;
        __syncthreads();
        FragU fa[4], fb[2];
        #pragma unroll
        for (int i=0;i<4;i++) fa[i].s = *(short8*)&As[(quad*128 + wm*64 + i*16 + lm)*8];
        #pragma unroll
        for (int j=0;j<2;j++) fb[j].s = *(short8*)&Bs[(wn*32 + j*16 + lm)*40 + quad*8];
        #pragma unroll
        for (int i=0;i<4;i++)
            #pragma unroll
            for (int j=0;j<2;j++)
                acc[i][j] = __builtin_amdgcn_mfma_f32_16x16x32_bf16(fa[i].b, fb[j].b, acc[i][j], 0,0,0);
    }
    #pragma unroll
    for (int i=0;i<4;i++)
        #pragma unroll
        for (int j=0;j<2;j++) {
            int col = col0 + wn*32 + j*16 + lm;
            float bb = bias ? bias[col] : 0.f;
            #pragma unroll
            for (int r=0;r<4;r++) {
                int row = row0 + wm*64 + i*16 + quad*4 + r;
                C[(size_t)row*ldc + col] = acc[i][j][r] + bb;
            }
        }
}

__global__ __launch_bounds__(256) void gemm_mfma_acc(
    const float* __restrict__ A, int lda,
    const float* __restrict__ B, int ldb, long sB,
    const int* __restrict__ offs, const int* __restrict__ perm,
    float* __restrict__ Cacc, int ldc, int K)
{
    const int e  = blockIdx.z >> 1;
    const int sk = blockIdx.z & 1;
    int off = 0, Ne = T_;
    if (offs) { off = offs[e]; Ne = offs[e+1] - off; }
    const int row0 = blockIdx.y * 128;
    if (row0 >= Ne) return;
    const int col0 = blockIdx.x * 64;
    B += (long)e * sB;

    __shared__ __align__(16) short As[4*128*8];
    __shared__ __align__(16) short Bs[64*40];
    __shared__ int toks[128];
    GEMM_IDS
    if (tid < 128) {
        int r = row0 + tid;
        toks[tid] = offs ? ((r < Ne) ? perm[off + r] : -1) : r;
    }
    __syncthreads();

    floatx4 acc[4][2];
    #pragma unroll
    for (int i=0;i<4;i++)
        #pragma unroll
        for (int j=0;j<2;j++) acc[i][j] = (floatx4){0.f,0.f,0.f,0.f};

    const int tokA = toks[a_m];
    const float* apx = (tokA >= 0) ? (A + (size_t)tokA * lda + a_kh) : nullptr;
    const float* bpx = B + (size_t)(b_kc*8) * ldb + col0 + b_n;
    const int kcA = (tid & 1) * 2;
    const int koff = sk * (K >> 1), kend = koff + (K >> 1);

    for (int k0 = koff; k0 < kend; k0 += 32) {
        float4 a0 = make_float4(0,0,0,0), a1 = a0, a2 = a0, a3 = a0;
        if (apx) {
            a0 = *(const float4*)(apx + k0);
            a1 = *(const float4*)(apx + k0 + 4);
            a2 = *(const float4*)(apx + k0 + 8);
            a3 = *(const float4*)(apx + k0 + 12);
        }
        float bvv[8];
        const float* bp = bpx + (size_t)k0 * ldb;
        #pragma unroll
        for (int j=0;j<8;j++) bvv[j] = bp[(size_t)j*ldb];
        __syncthreads();
        short8 c0, c1, cb;
        cvt16(a0,a1,a2,a3,c0,c1);
        #pragma unroll
        for (int j=0;j<8;j++) cb[j] = f2bf(bvv[j]);
        *(short8*)&As[((kcA  )*128 + a_m)*8] = c0;
        *(short8*)&As[((kcA+1)*128 + a_m)*8] = c1;
        *(short8*)&Bs[b_n*40 + b_kc*8] = cb;
        __syncthreads();
        FragU fa[4], fb[2];
        #pragma unroll
        for (int i=0;i<4;i++) fa[i].s = *(short8*)&As[(quad*128 + wm*64 + i*16 + lm)*8];
        #pragma unroll
        for (int j=0;j<2;j++) fb[j].s = *(short8*)&Bs[(wn*32 + j*16 + lm)*40 + quad*8];
        #pragma unroll
        for (int i=0;i<4;i++)
            #pragma unroll
            for (int j=0;j<2;j++)
                acc[i][j] = __builtin_amdgcn_mfma_f32_16x16x32_bf16(fa[i].b, fb[j].b, acc[i][j], 0,0,0);
    }
    #pragma unroll
    for (int i=0;i<4;i++)
        #pragma unroll
        for (int j=0;j<2;j++) {
            int col = col0 + wn*32 + j*16 + lm;
            #pragma unroll
            for (int r=0;r<4;r++) {
                int tk = toks[wm*64 + i*16 + quad*4 + r];
                if (tk >= 0) atomicAdd(&Cacc[(size_t)tk*ldc + col], acc[i][j][r]);
            }
        }
}

__global__ __launch_bounds__(256) void moe_fc_mfma(
    const float* __restrict__ h2, const float* __restrict__ fcw,
    const float* __restrict__ fcb, const int* __restrict__ offs,
    const int* __restrict__ perm, float* __restrict__ aout)
{
    const int e = blockIdx.z;
    const int off = offs[e];
    const int Ne = offs[e+1] - off;
    const int row0 = blockIdx.y * 128;
    if (row0 >= Ne) return;
    const int col0 = blockIdx.x * 64;

    __shared__ __align__(16) short As[4*128*8];
    __shared__ __align__(16) short B1s[64*40];
    __shared__ __align__(16) short B2s[64*40];
    __shared__ int toks[128];
    GEMM_IDS
    if (tid < 128) {
        int r = row0 + tid;
        toks[tid] = (r < Ne) ? perm[off + r] : -1;
    }
    __syncthreads();

    floatx4 acc1[4][2], acc2[4][2];
    #pragma unroll
    for (int i=0;i<4;i++)
        #pragma unroll
        for (int j=0;j<2;j++) {
            acc1[i][j] = (floatx4){0.f,0.f,0.f,0.f};
            acc2[i][j] = (floatx4){0.f,0.f,0.f,0.f};
        }

    const float* W = fcw + (size_t)e * D_ * F2_;
    const int tokA = toks[a_m];
    const float* apx = (tokA >= 0) ? (h2 + (size_t)tokA * D_ + a_kh) : nullptr;
    const float* bpx = W + (size_t)(b_kc*8) * F2_ + col0 + b_n;
    const int kcA = (tid & 1) * 2;

    for (int k0 = 0; k0 < D_; k0 += 32) {
        float4 a0 = make_float4(0,0,0,0), a1 = a0, a2 = a0, a3 = a0;
        if (apx) {
            a0 = *(const float4*)(apx + k0);
            a1 = *(const float4*)(apx + k0 + 4);
            a2 = *(const float4*)(apx + k0 + 8);
            a3 = *(const float4*)(apx + k0 + 12);
        }
        float bv1[8], bv2[8];
        const float* bp = bpx + (size_t)k0 * F2_;
        #pragma unroll
        for (int j=0;j<8;j++) { bv1[j] = bp[(size_t)j*F2_]; bv2[j] = bp[(size_t)j*F2_ + F_]; }
        __syncthreads();
        short8 c0, c1, cb1, cb2;
        cvt16(a0,a1,a2,a3,c0,c1);
        #pragma unroll
        for (int j=0;j<8;j++) { cb1[j] = f2bf(bv1[j]); cb2[j] = f2bf(bv2[j]); }
        *(short8*)&As[((kcA  )*128 + a_m)*8] = c0;
        *(short8*)&As[((kcA+1)*128 + a_m)*8] = c1;
        *(short8*)&B1s[b_n*40 + b_kc*8] = cb1;
        *(short8*)&B2s[b_n*40 + b_kc*8] = cb2;
        __syncthreads();
        FragU fa[4], fb1[2], fb2[2];
        #pragma unroll
        for (int i=0;i<4;i++) fa[i].s = *(short8*)&As[(quad*128 + wm*64 + i*16 + lm)*8];
        #pragma unroll
        for (int j=0;j<2;j++) {
            fb1[j].s = *(short8*)&B1s[(wn*32 + j*16 + lm)*40 + quad*8];
            fb2[j].s = *(short8*)&B2s[(wn*32 + j*16 + lm)*40 + quad*8];
        }
        #pragma unroll
        for (int i=0;i<4;i++)
            #pragma unroll
            for (int j=0;j<2;j++) {
                acc1[i][j] = __builtin_amdgcn_mfma_f32_16x16x32_bf16(fa[i].b, fb1[j].b, acc1[i][j], 0,0,0);
                acc2[i][j] = __builtin_amdgcn_mfma_f32_16x16x32_bf16(fa[i].b, fb2[j].b, acc2[i][j], 0,0,0);
            }
    }
    #pragma unroll
    for (int i=0;i<4;i++)
        #pragma unroll
        for (int j=0;j<2;j++) {
            int col = col0 + wn*32 + j*16 + lm;
            float b1 = fcb[(size_t)e*F2_ + col];
            float b2 = fcb[(size_t)e*F2_ + F_ + col];
            #pragma unroll
            for (int r=0;r<4;r++) {
                int tk = toks[wm*64 + i*16 + quad*4 + r];
                if (tk < 0) continue;
                float v1 = acc1[i][j][r] + b1;
                float v2 = acc2[i][j][r] + b2;
                float g = v2 * 0.5f * (1.0f + erff(v2 * 0.70710678118654752f));
                aout[(size_t)tk*F_ + col] = v1 * g;
            }
        }
}

// ===================== MFMA flash attention =====================
// Block: 128 thr = 2 waves; 1 head, 32 queries (wave w -> 16 rows).
// KV tiles of 64 keys staged in LDS bf16: Ks[key][72], Vt[dim][72].
// QK^T: A=Q frag (reg, loaded once), B=K^T from Ks. S in C-layout.
// Online softmax per quad-row, P -> LDS (A-layout round trip) -> PV MFMA.
__global__ __launch_bounds__(128) void flash_attn(
    const float* __restrict__ qkv, const int* __restrict__ ids,
    float* __restrict__ attnout)
{
    const int h  = blockIdx.y;
    const int q0 = blockIdx.x * 32;
    const int tid = threadIdx.x;
    const int lane = tid & 63, w = tid >> 6;
    const int quad = lane >> 4, lm = lane & 15;

    __shared__ __align__(16) short Qs[32*72];
    __shared__ __align__(16) short Ks[64*72];
    __shared__ __align__(16) short Vt[64*72];
    __shared__ __align__(16) short Ps[2][16*72];
    __shared__ int globf[32];

    // ---- stage Q (once) + glob flags ----
    {
        int row = tid >> 2, c = (tid & 3) * 16;
        const float* qp = qkv + (size_t)(q0 + row) * D3_ + h * HD_ + c;
        float4 f0 = *(const float4*)(qp);
        float4 f1 = *(const float4*)(qp + 4);
        float4 f2 = *(const float4*)(qp + 8);
        float4 f3 = *(const float4*)(qp + 12);
        short8 s0, s1;
        cvt16(f0, f1, f2, f3, s0, s1);
        *(short8*)&Qs[row*72 + c]     = s0;
        *(short8*)&Qs[row*72 + c + 8] = s1;
    }
    if (tid < 32) {
        int id = ids[q0 + tid];
        globf[tid] = (id >= 2 && id <= 7) ? 1 : 0;
    }
    __syncthreads();

    FragU QA[2];
    #pragma unroll
    for (int s = 0; s < 2; s++)
        QA[s].s = *(short8*)&Qs[(w*16 + lm)*72 + s*32 + quad*8];

    int any = 0;
    #pragma unroll
    for (int i = 0; i < 32; i++) any |= globf[i];
    const int nt = any ? (T_/64) : ((q0 + 31) >> 6) + 1;

    int gq[4]; int qidx[4];
    #pragma unroll
    for (int r = 0; r < 4; r++) {
        int ql = w*16 + quad*4 + r;
        qidx[r] = q0 + ql;
        gq[r] = globf[ql];
    }

    float mrow[4] = {-1e30f, -1e30f, -1e30f, -1e30f};
    float lrow[4] = {0.f, 0.f, 0.f, 0.f};
    floatx4 Oacc[4];
    #pragma unroll
    for (int n = 0; n < 4; n++) Oacc[n] = (floatx4){0.f, 0.f, 0.f, 0.f};

    for (int kt = 0; kt < nt; kt++) {
        __syncthreads();
        // ---- stage K tile ----
        #pragma unroll
        for (int rep = 0; rep < 2; rep++) {
            int key = (tid >> 2) + rep*32;
            int c = (tid & 3) * 16;
            const float* kp = qkv + (size_t)(kt*64 + key) * D3_ + D_ + h*HD_ + c;
            float4 f0 = *(const float4*)(kp);
            float4 f1 = *(const float4*)(kp + 4);
            float4 f2 = *(const float4*)(kp + 8);
            float4 f3 = *(const float4*)(kp + 12);
            short8 s0, s1;
            cvt16(f0, f1, f2, f3, s0, s1);
            *(short8*)&Ks[key*72 + c]     = s0;
            *(short8*)&Ks[key*72 + c + 8] = s1;
        }
        // ---- stage V tile (transposed) ----
        #pragma unroll
        for (int rep = 0; rep < 8; rep++) {
            int lin = tid + rep*128;
            int key = lin >> 4;
            int c = (lin & 15) * 4;
            const float* vp = qkv + (size_t)(kt*64 + key) * D3_ + 2*D_ + h*HD_ + c;
            float4 f = *(const float4*)vp;
            Vt[(c+0)*72 + key] = f2bf(f.x);
            Vt[(c+1)*72 + key] = f2bf(f.y);
            Vt[(c+2)*72 + key] = f2bf(f.z);
            Vt[(c+3)*72 + key] = f2bf(f.w);
        }
        __syncthreads();

        // ---- S = Q K^T ----
        floatx4 Sv[4];
        #pragma unroll
        for (int n = 0; n < 4; n++) {
            Sv[n] = (floatx4){0.f, 0.f, 0.f, 0.f};
            #pragma unroll
            for (int s = 0; s < 2; s++) {
                FragU KB;
                KB.s = *(short8*)&Ks[(n*16 + lm)*72 + s*32 + quad*8];
                Sv[n] = __builtin_amdgcn_mfma_f32_16x16x32_bf16(QA[s].b, KB.b, Sv[n], 0, 0, 0);
            }
        }
        // ---- scale + mask ----
        #pragma unroll
        for (int n = 0; n < 4; n++) {
            int key = kt*64 + n*16 + lm;
            #pragma unroll
            for (int r = 0; r < 4; r++) {
                float v = Sv[n][r] * 0.125f;
                if (!gq[r] && key > qidx[r]) v = -1e30f;
                Sv[n][r] = v;
            }
        }
        // ---- online softmax ----
        float mnew[4], alpha[4], tsum[4];
        #pragma unroll
        for (int r = 0; r < 4; r++) {
            float tm = fmaxf(fmaxf(Sv[0][r], Sv[1][r]), fmaxf(Sv[2][r], Sv[3][r]));
            #pragma unroll
            for (int x = 1; x < 16; x <<= 1) tm = fmaxf(tm, __shfl_xor(tm, x));
            mnew[r] = fmaxf(mrow[r], tm);
            alpha[r] = __expf(mrow[r] - mnew[r]);
            mrow[r] = mnew[r];
            tsum[r] = 0.f;
        }
        #pragma unroll
        for (int n = 0; n < 4; n++) {
            #pragma unroll
            for (int r = 0; r < 4; r++) {
                float p = __expf(Sv[n][r] - mnew[r]);
                tsum[r] += p;
                Ps[w][(quad*4 + r)*72 + n*16 + lm] = f2bf(p);
            }
        }
        #pragma unroll
        for (int r = 0; r < 4; r++) {
            #pragma unroll
            for (int x = 1; x < 16; x <<= 1) tsum[r] += __shfl_xor(tsum[r], x);
            lrow[r] = lrow[r] * alpha[r] + tsum[r];
        }
        #pragma unroll
        for (int n = 0; n < 4; n++)
            #pragma unroll
            for (int r = 0; r < 4; r++) Oacc[n][r] *= alpha[r];

        // ---- O += P V ----
        #pragma unroll
        for (int s = 0; s < 2; s++) {
            FragU PA;
            PA.s = *(short8*)&Ps[w][lm*72 + s*32 + quad*8];
            #pragma unroll
            for (int n = 0; n < 4; n++) {
                FragU VB;
                VB.s = *(short8*)&Vt[(n*16 + lm)*72 + s*32 + quad*8];
                Oacc[n] = __builtin_amdgcn_mfma_f32_16x16x32_bf16(PA.b, VB.b, Oacc[n], 0, 0, 0);
            }
        }
    }

    // ---- epilogue ----
    #pragma unroll
    for (int n = 0; n < 4; n++)
        #pragma unroll
        for (int r = 0; r < 4; r++) {
            float o = Oacc[n][r] / lrow[r];
            attnout[(size_t)qidx[r]*D_ + h*HD_ + n*16 + lm] = o;
        }
}

// ===================== epilogues =====================
__global__ __launch_bounds__(256) void ep_attn(
    const float* __restrict__ x, const float* __restrict__ sacc,
    const float* __restrict__ aob, float* __restrict__ x2)
{
    int row = blockIdx.x, tid = threadIdx.x;
    float4 xv = ((const float4*)(x + (size_t)row*D_))[tid];
    float4 sv = ((const float4*)(sacc + (size_t)row*D_))[tid];
    float4 bv = ((const float4*)aob)[tid];
    float4 o;
    o.x = xv.x + sv.x + bv.x; o.y = xv.y + sv.y + bv.y;
    o.z = xv.z + sv.z + bv.z; o.w = xv.w + sv.w + bv.w;
    ((float4*)(x2 + (size_t)row*D_))[tid] = o;
}

__global__ __launch_bounds__(256) void ep_moe(
    const float* __restrict__ x2, const float* __restrict__ sacc,
    const float* __restrict__ eob, const float* __restrict__ gw,
    const int* __restrict__ gi, float* __restrict__ out)
{
    int row = blockIdx.x, tid = threadIdx.x;
    float g = gw[row];
    int e = gi[row];
    float4 xv = ((const float4*)(x2 + (size_t)row*D_))[tid];
    float4 sv = ((const float4*)(sacc + (size_t)row*D_))[tid];
    float4 bv = ((const float4*)(eob + (size_t)e*D_))[tid];
    float4 o;
    o.x = xv.x + g*(sv.x + bv.x); o.y = xv.y + g*(sv.y + bv.y);
    o.z = xv.z + g*(sv.z + bv.z); o.w = xv.w + g*(sv.w + bv.w);
    ((float4*)(out + (size_t)row*D_))[tid] = o;
}

// ===================== small kernels =====================
__global__ __launch_bounds__(256) void ln_kernel(
    const float* __restrict__ x, const float* __restrict__ w,
    const float* __restrict__ b, float* __restrict__ out)
{
    const int row = blockIdx.x, tid = threadIdx.x;
    const int lane = tid & 63, wave = tid >> 6;
    float4 v = ((const float4*)(x + (size_t)row * D_))[tid];
    float s  = v.x + v.y + v.z + v.w;
    float sq = v.x*v.x + v.y*v.y + v.z*v.z + v.w*v.w;
    #pragma unroll
    for (int off = 32; off; off >>= 1) {
        s  += __shfl_down(s, off);
        sq += __shfl_down(sq, off);
    }
    __shared__ float rs[4], rq[4], mv[2];
    if (lane == 0) { rs[wave] = s; rq[wave] = sq; }
    __syncthreads();
    if (tid == 0) {
        float ts = rs[0]+rs[1]+rs[2]+rs[3];
        float tq = rq[0]+rq[1]+rq[2]+rq[3];
        float mean = ts * (1.0f / D_);
        float var  = tq * (1.0f / D_) - mean*mean;
        mv[0] = mean; mv[1] = rsqrtf(var + 1e-5f);
    }
    __syncthreads();
    float mean = mv[0], rstd = mv[1];
    float4 wv = ((const float4*)w)[tid];
    float4 bv = ((const float4*)b)[tid];
    float4 o;
    o.x = (v.x-mean)*rstd*wv.x + bv.x;
    o.y = (v.y-mean)*rstd*wv.y + bv.y;
    o.z = (v.z-mean)*rstd*wv.z + bv.z;
    o.w = (v.w-mean)*rstd*wv.w + bv.w;
    ((float4*)(out + (size_t)row * D_))[tid] = o;
}

__global__ __launch_bounds__(256) void rope_kernel(float* __restrict__ qkv)
{
    int gid = blockIdx.x * 256 + threadIdx.x;
    int t = gid >> 9;
    int r = gid & 511;
    int h = r >> 5;
    int d = r & 31;
    float inv = powf(10000.0f, -(float)d * (1.0f/32.0f));
    float fr = (float)t * inv;
    float s, c;
    sincosf(fr, &s, &c);
    float* base = qkv + (size_t)t*D3_ + h*HD_ + d;
    float q1 = base[0], q2 = base[32];
    base[0]  = q1*c - q2*s;
    base[32] = q1*s + q2*c;
    float* kb = base + D_;
    float k1 = kb[0], k2 = kb[32];
    kb[0]  = k1*c - k2*s;
    kb[32] = k1*s + k2*c;
}

__global__ __launch_bounds__(256) void ln2_gate_kernel(
    const float* __restrict__ x2, const float* __restrict__ w,
    const float* __restrict__ b, const float* __restrict__ gwm,
    const float* __restrict__ gbv, float* __restrict__ h2,
    int* __restrict__ gi, float* __restrict__ gw)
{
    const int row = blockIdx.x, tid = threadIdx.x;
    const int lane = tid & 63, wave = tid >> 6;
    float4 v = ((const float4*)(x2 + (size_t)row * D_))[tid];
    float s  = v.x + v.y + v.z + v.w;
    float sq = v.x*v.x + v.y*v.y + v.z*v.z + v.w*v.w;
    #pragma unroll
    for (int off = 32; off; off >>= 1) {
        s  += __shfl_down(s, off);
        sq += __shfl_down(sq, off);
    }
    __shared__ float rs[4], rq[4], mv[2];
    if (lane == 0) { rs[wave] = s; rq[wave] = sq; }
    __syncthreads();
    if (tid == 0) {
        float ts = rs[0]+rs[1]+rs[2]+rs[3];
        float tq = rq[0]+rq[1]+rq[2]+rq[3];
        float mean = ts * (1.0f / D_);
        float var  = tq * (1.0f / D_) - mean*mean;
        mv[0] = mean; mv[1] = rsqrtf(var + 1e-5f);
    }
    __syncthreads();
    float mean = mv[0], rstd = mv[1];
    float4 wv = ((const float4*)w)[tid];
    float4 bv = ((const float4*)b)[tid];
    float hv[4];
    hv[0] = (v.x-mean)*rstd*wv.x + bv.x;
    hv[1] = (v.y-mean)*rstd*wv.y + bv.y;
    hv[2] = (v.z-mean)*rstd*wv.z + bv.z;
    hv[3] = (v.w-mean)*rstd*wv.w + bv.w;
    float4 o; o.x=hv[0]; o.y=hv[1]; o.z=hv[2]; o.w=hv[3];
    ((float4*)(h2 + (size_t)row * D_))[tid] = o;

    float acc[E_] = {};
    int c = tid * 4;
    #pragma unroll
    for (int j = 0; j < 4; j++) {
        const float* gr = gwm + (size_t)(c+j) * E_;
        #pragma unroll
        for (int e = 0; e < E_; e++) acc[e] += hv[j] * gr[e];
    }
    #pragma unroll
    for (int off = 32; off; off >>= 1)
        #pragma unroll
        for (int e = 0; e < E_; e++) acc[e] += __shfl_down(acc[e], off);
    __shared__ float gred[4][E_];
    if (lane == 0)
        for (int e = 0; e < E_; e++) gred[wave][e] = acc[e];
    __syncthreads();
    if (tid == 0) {
        float lg[E_];
        float mxl = -FLT_MAX; int mi = 0;
        for (int e = 0; e < E_; e++)
            lg[e] = gred[0][e]+gred[1][e]+gred[2][e]+gred[3][e] + gbv[e];
        for (int e = 0; e < E_; e++)
            if (lg[e] > mxl) { mxl = lg[e]; mi = e; }
        float ssum = 0.f;
        for (int e = 0; e < E_; e++) ssum += expf(lg[e] - mxl);
        gi[row] = mi;
        gw[row] = 1.0f / ssum;
    }
}

__global__ void route_kernel(const int* __restrict__ gi,
                             int* __restrict__ offs, int* __restrict__ perm)
{
    __shared__ int cnt[E_], c2[E_], off[E_+1];
    const int tid = threadIdx.x;
    if (tid < E_) { cnt[tid] = 0; c2[tid] = 0; }
    __syncthreads();
    int e = gi[tid];
    atomicAdd(&cnt[e], 1);
    __syncthreads();
    if (tid == 0) {
        off[0] = 0;
        for (int i = 0; i < E_; i++) off[i+1] = off[i] + cnt[i];
        for (int i = 0; i <= E_; i++) offs[i] = off[i];
    }
    __syncthreads();
    int r = atomicAdd(&c2[e], 1);
    perm[off[e] + r] = tid;
}

__global__ void loss_kernel(const int* __restrict__ gi,
                            const float* __restrict__ gw, float* __restrict__ out)
{
    __shared__ float ss[E_], sc[E_];
    const int tid = threadIdx.x;
    if (tid < E_) { ss[tid] = 0.f; sc[tid] = 0.f; }
    __syncthreads();
    for (int t = tid; t < T_; t += 256) {
        int e = gi[t];
        atomicAdd(&ss[e], gw[t]);
        atomicAdd(&sc[e], 1.0f);
    }
    __syncthreads();
    if (tid == 0) {
        float loss = 0.f;
        for (int e = 0; e < E_; e++) {
            float u = ss[e] / (sc[e] + 1e-8f);
            float d = u - 0.125f;
            loss += d * d;
        }
        out[(size_t)T_ * D_] = loss;
    }
}

extern "C" void kernel_launch(void* const* d_in, const int* in_sizes, int n_in,
                              void* d_out, int out_size, void* d_ws, size_t ws_size,
                              hipStream_t stream)
{
    const float* x     = (const float*)d_in[0];
    const int*   ids   = (const int*)d_in[1];
    const float* ln1w  = (const float*)d_in[2];
    const float* ln1b  = (const float*)d_in[3];
    const float* qkvw  = (const float*)d_in[4];
    const float* qkvb  = (const float*)d_in[5];
    const float* aow   = (const float*)d_in[6];
    const float* aob   = (const float*)d_in[7];
    const float* ln2w  = (const float*)d_in[8];
    const float* ln2b  = (const float*)d_in[9];
    const float* gatew = (const float*)d_in[10];
    const float* gateb = (const float*)d_in[11];
    const float* fcw   = (const float*)d_in[12];
    const float* fcb   = (const float*)d_in[13];
    const float* eoutw = (const float*)d_in[14];
    const float* eoutb = (const float*)d_in[15];
    float* out = (float*)d_out;
    float* ws  = (float*)d_ws;

    float* h    = ws + WS_H;      // reused as SACC after qkv GEMM
    float* sacc = ws + WS_H;
    float* qkv  = ws + WS_QKV;
    float* attn = ws + WS_ATTN;
    float* x2   = ws + WS_X2;
    float* h2   = ws + WS_H2;
    float* abuf = ws + WS_A;
    float* gw   = ws + WS_GW;
    int*   gi   = (int*)(ws + WS_GI);
    int*   offs = (int*)(ws + WS_OFFS);
    int*   perm = (int*)(ws + WS_PERM);

    // 1. LN1
    ln_kernel<<<T_, 256, 0, stream>>>(x, ln1w, ln1b, h);
    // 2. QKV projection (MFMA)
    gemm_mfma_full<<<dim3(D3_/64, T_/128), 256, 0, stream>>>(
        h, D_, qkvw, D3_, qkvb, qkv, D3_, D_);
    // 3. RoPE
    rope_kernel<<<(T_*H_*32)/256, 256, 0, stream>>>(qkv);
    // 4. MFMA flash attention
    flash_attn<<<dim3(T_/32, H_), 128, 0, stream>>>(qkv, ids, attn);
    // 5. zero split-K accumulator (h is dead now)
    hipMemsetAsync(sacc, 0, (size_t)T_*D_*sizeof(float), stream);
    // 6. attn output projection (MFMA, split-K=2, accumulate)
    gemm_mfma_acc<<<dim3(D_/64, T_/128, 2), 256, 0, stream>>>(
        attn, D_, aow, D_, 0, nullptr, nullptr, sacc, D_, D_);
    // 7. residual + bias
    ep_attn<<<T_, 256, 0, stream>>>(x, sacc, aob, x2);
    // 8. LN2 + gate
    ln2_gate_kernel<<<T_, 256, 0, stream>>>(x2, ln2w, ln2b, gatew, gateb, h2, gi, gw);
    // 9. routing
    route_kernel<<<1, T_, 0, stream>>>(gi, offs, perm);
    // 10. expert fc + GLU (MFMA)
    moe_fc_mfma<<<dim3(F_/64, T_/128, E_), 256, 0, stream>>>(h2, fcw, fcb, offs, perm, abuf);
    // 11. re-zero accumulator
    hipMemsetAsync(sacc, 0, (size_t)T_*D_*sizeof(float), stream);
    // 12. expert out (MFMA, split-K=2, routed accumulate)
    gemm_mfma_acc<<<dim3(D_/64, T_/128, 2*E_), 256, 0, stream>>>(
        abuf, F_, eoutw, D_, (long)F_*D_, offs, perm, sacc, D_, F_);
    // 13. residual + gate scale + bias
    ep_moe<<<T_, 256, 0, stream>>>(x2, sacc, eoutb, gw, gi, out);
    // 14. aux loss
    loss_kernel<<<1, 256, 0, stream>>>(gi, gw, out);
}

// Round 4
// 592.575 us; speedup vs baseline: 2.3888x; 1.1611x over previous
//
#include <hip/hip_runtime.h>
#include <float.h>
#include <math.h>
#include <stdint.h>

#define T_ 1024
#define D_ 1024
#define H_ 16
#define HD_ 64
#define E_ 8
#define F_ 2560
#define D3_ 3072
#define F2_ 5120

// ---- workspace layout (float offsets) ----
#define WS_H    0u         // 1M   LN1 out; later reused as SACC (split-K accum)
#define WS_QKV  1048576u   // 3M   qkv (T,3D)
#define WS_ATTN 4194304u   // 1M   attention out (T,D)
#define WS_X2   5242880u   // 1M   x + attn proj (T,D)
#define WS_H2   6291456u   // 1M   LN2 out
#define WS_A    7340032u   // 2.62M gated activation (T,F)
#define WS_GW   9961472u
#define WS_GI   9962496u
#define WS_OFFS 9963520u
#define WS_PERM 9963536u

typedef short short8 __attribute__((ext_vector_type(8)));
typedef short short4v __attribute__((ext_vector_type(4)));
typedef __bf16 bf16x8 __attribute__((ext_vector_type(8)));
typedef float floatx4 __attribute__((ext_vector_type(4)));

union FragU { short8 s; bf16x8 b; };

__device__ __forceinline__ short f2bf(float f) {
    union { float f; uint32_t u; } a; a.f = f;
    uint32_t r = a.u + 0x7fffu + ((a.u >> 16) & 1u);
    return (short)(r >> 16);
}

__device__ __forceinline__ void cvt16(const float4& a0, const float4& a1,
                                      const float4& a2, const float4& a3,
                                      short8& c0, short8& c1) {
    c0[0]=f2bf(a0.x); c0[1]=f2bf(a0.y); c0[2]=f2bf(a0.z); c0[3]=f2bf(a0.w);
    c0[4]=f2bf(a1.x); c0[5]=f2bf(a1.y); c0[6]=f2bf(a1.z); c0[7]=f2bf(a1.w);
    c1[0]=f2bf(a2.x); c1[1]=f2bf(a2.y); c1[2]=f2bf(a2.z); c1[3]=f2bf(a2.w);
    c1[4]=f2bf(a3.x); c1[5]=f2bf(a3.y); c1[6]=f2bf(a3.z); c1[7]=f2bf(a3.w);
}

// ===================== MFMA GEMM cores (register-pipelined) =====================
// Tile: BM=128, BN=64, BK=32. 256 thr = 4 waves (2x2), wave tile 64x32.
#define GEMM_IDS \
    const int tid  = threadIdx.x;                 \
    const int a_m  = tid >> 1;                    \
    const int a_kh = (tid & 1) * 16;              \
    const int lane = tid & 63, wave = tid >> 6;   \
    const int wm = wave & 1,  wn = wave >> 1;     \
    const int quad = lane >> 4, lm = lane & 15;

__global__ __launch_bounds__(256) void gemm_mfma_full(
    const float* __restrict__ A, int lda,
    const float* __restrict__ B, int ldb,
    const float* __restrict__ bias,
    float* __restrict__ C, int ldc, int K)
{
    __shared__ __align__(16) short As[4*128*8];
    __shared__ __align__(16) short Bs[64*40];
    const int row0 = blockIdx.y * 128, col0 = blockIdx.x * 64;
    GEMM_IDS
    const int b_n = tid >> 2, b_kc = tid & 3;
    floatx4 acc[4][2];
    #pragma unroll
    for (int i=0;i<4;i++)
        #pragma unroll
        for (int j=0;j<2;j++) acc[i][j] = (floatx4){0.f,0.f,0.f,0.f};

    const float* apx = A + (size_t)(row0 + a_m) * lda + a_kh;
    const float* bpx = B + (size_t)(b_kc*8) * ldb + col0 + b_n;
    const int kcA = (tid & 1) * 2;

    float4 a0, a1, a2, a3; float bvv[8];
    // preload k=0
    a0 = *(const float4*)(apx);     a1 = *(const float4*)(apx + 4);
    a2 = *(const float4*)(apx + 8); a3 = *(const float4*)(apx + 12);
    #pragma unroll
    for (int j=0;j<8;j++) bvv[j] = bpx[(size_t)j*ldb];

    for (int k0 = 0; k0 < K; k0 += 32) {
        __syncthreads();
        short8 c0, c1, cb;
        cvt16(a0,a1,a2,a3,c0,c1);
        #pragma unroll
        for (int j=0;j<8;j++) cb[j] = f2bf(bvv[j]);
        *(short8*)&As[((kcA  )*128 + a_m)*8] = c0;
        *(short8*)&As[((kcA+1)*128 + a_m)*8] = c1;
        *(short8*)&Bs[b_n*40 + b_kc*8] = cb;
        __syncthreads();
        if (k0 + 32 < K) {   // prefetch next tile (overlaps MFMA below)
            const float* ap2 = apx + k0 + 32;
            a0 = *(const float4*)(ap2);     a1 = *(const float4*)(ap2 + 4);
            a2 = *(const float4*)(ap2 + 8); a3 = *(const float4*)(ap2 + 12);
            const float* bp2 = bpx + (size_t)(k0+32) * ldb;
            #pragma unroll
            for (int j=0;j<8;j++) bvv[j] = bp2[(size_t)j*ldb];
        }
        FragU fa[4], fb[2];
        #pragma unroll
        for (int i=0;i<4;i++) fa[i].s = *(short8*)&As[(quad*128 + wm*64 + i*16 + lm)*8];
        #pragma unroll
        for (int j=0;j<2;j++) fb[j].s = *(short8*)&Bs[(wn*32 + j*16 + lm)*40 + quad*8];
        #pragma unroll
        for (int i=0;i<4;i++)
            #pragma unroll
            for (int j=0;j<2;j++)
                acc[i][j] = __builtin_amdgcn_mfma_f32_16x16x32_bf16(fa[i].b, fb[j].b, acc[i][j], 0,0,0);
    }
    #pragma unroll
    for (int i=0;i<4;i++)
        #pragma unroll
        for (int j=0;j<2;j++) {
            int col = col0 + wn*32 + j*16 + lm;
            float bb = bias ? bias[col] : 0.f;
            #pragma unroll
            for (int r=0;r<4;r++) {
                int row = row0 + wm*64 + i*16 + quad*4 + r;
                C[(size_t)row*ldc + col] = acc[i][j][r] + bb;
            }
        }
}

// split-K accumulating GEMM (optionally token-routed): Cacc += A@B
// blockIdx.z: sk = z % nsk, e = z / nsk.
__global__ __launch_bounds__(256) void gemm_mfma_acc(
    const float* __restrict__ A, int lda,
    const float* __restrict__ B, int ldb, long sB,
    const int* __restrict__ offs, const int* __restrict__ perm,
    float* __restrict__ Cacc, int ldc, int K, int nsk)
{
    const int sk = blockIdx.z % nsk;
    const int e  = blockIdx.z / nsk;
    int off = 0, Ne = T_;
    if (offs) { off = offs[e]; Ne = offs[e+1] - off; }
    const int row0 = blockIdx.y * 128;
    if (row0 >= Ne) return;
    const int col0 = blockIdx.x * 64;
    B += (long)e * sB;

    __shared__ __align__(16) short As[4*128*8];
    __shared__ __align__(16) short Bs[64*40];
    __shared__ int toks[128];
    GEMM_IDS
    const int b_n = tid >> 2, b_kc = tid & 3;
    if (tid < 128) {
        int r = row0 + tid;
        toks[tid] = offs ? ((r < Ne) ? perm[off + r] : -1) : r;
    }
    __syncthreads();

    floatx4 acc[4][2];
    #pragma unroll
    for (int i=0;i<4;i++)
        #pragma unroll
        for (int j=0;j<2;j++) acc[i][j] = (floatx4){0.f,0.f,0.f,0.f};

    const int tokA = toks[a_m];
    const float* apx = (tokA >= 0) ? (A + (size_t)tokA * lda + a_kh) : nullptr;
    const float* bpx = B + (size_t)(b_kc*8) * ldb + col0 + b_n;
    const int kcA = (tid & 1) * 2;
    const int Kp = K / nsk;
    const int koff = sk * Kp, kend = koff + Kp;

    float4 a0, a1, a2, a3; float bvv[8];
    a0 = make_float4(0,0,0,0); a1 = a0; a2 = a0; a3 = a0;
    if (apx) {
        a0 = *(const float4*)(apx + koff);     a1 = *(const float4*)(apx + koff + 4);
        a2 = *(const float4*)(apx + koff + 8); a3 = *(const float4*)(apx + koff + 12);
    }
    {
        const float* bp2 = bpx + (size_t)koff * ldb;
        #pragma unroll
        for (int j=0;j<8;j++) bvv[j] = bp2[(size_t)j*ldb];
    }

    for (int k0 = koff; k0 < kend; k0 += 32) {
        __syncthreads();
        short8 c0, c1, cb;
        cvt16(a0,a1,a2,a3,c0,c1);
        #pragma unroll
        for (int j=0;j<8;j++) cb[j] = f2bf(bvv[j]);
        *(short8*)&As[((kcA  )*128 + a_m)*8] = c0;
        *(short8*)&As[((kcA+1)*128 + a_m)*8] = c1;
        *(short8*)&Bs[b_n*40 + b_kc*8] = cb;
        __syncthreads();
        if (k0 + 32 < kend) {
            if (apx) {
                const float* ap2 = apx + k0 + 32;
                a0 = *(const float4*)(ap2);     a1 = *(const float4*)(ap2 + 4);
                a2 = *(const float4*)(ap2 + 8); a3 = *(const float4*)(ap2 + 12);
            }
            const float* bp2 = bpx + (size_t)(k0+32) * ldb;
            #pragma unroll
            for (int j=0;j<8;j++) bvv[j] = bp2[(size_t)j*ldb];
        }
        FragU fa[4], fb[2];
        #pragma unroll
        for (int i=0;i<4;i++) fa[i].s = *(short8*)&As[(quad*128 + wm*64 + i*16 + lm)*8];
        #pragma unroll
        for (int j=0;j<2;j++) fb[j].s = *(short8*)&Bs[(wn*32 + j*16 + lm)*40 + quad*8];
        #pragma unroll
        for (int i=0;i<4;i++)
            #pragma unroll
            for (int j=0;j<2;j++)
                acc[i][j] = __builtin_amdgcn_mfma_f32_16x16x32_bf16(fa[i].b, fb[j].b, acc[i][j], 0,0,0);
    }
    #pragma unroll
    for (int i=0;i<4;i++)
        #pragma unroll
        for (int j=0;j<2;j++) {
            int col = col0 + wn*32 + j*16 + lm;
            #pragma unroll
            for (int r=0;r<4;r++) {
                int tk = toks[wm*64 + i*16 + quad*4 + r];
                if (tk >= 0) atomicAdd(&Cacc[(size_t)tk*ldc + col], acc[i][j][r]);
            }
        }
}

// MoE fc: BN=32-col pair (x1 col c, x2 col F_+c), wave tile 64x16, GLU epilogue.
__global__ __launch_bounds__(256) void moe_fc_mfma(
    const float* __restrict__ h2, const float* __restrict__ fcw,
    const float* __restrict__ fcb, const int* __restrict__ offs,
    const int* __restrict__ perm, float* __restrict__ aout)
{
    const int e = blockIdx.z;
    const int off = offs[e];
    const int Ne = offs[e+1] - off;
    const int row0 = blockIdx.y * 128;
    if (row0 >= Ne) return;
    const int col0 = blockIdx.x * 32;

    __shared__ __align__(16) short As[4*128*8];
    __shared__ __align__(16) short B1s[32*40];
    __shared__ __align__(16) short B2s[32*40];
    __shared__ int toks[128];
    GEMM_IDS
    const int n_l = tid & 31, kg = tid >> 5;   // B: col n_l, k-rows kg*4..+3
    if (tid < 128) {
        int r = row0 + tid;
        toks[tid] = (r < Ne) ? perm[off + r] : -1;
    }
    __syncthreads();

    floatx4 acc1[4], acc2[4];
    #pragma unroll
    for (int i=0;i<4;i++) {
        acc1[i] = (floatx4){0.f,0.f,0.f,0.f};
        acc2[i] = (floatx4){0.f,0.f,0.f,0.f};
    }

    const float* W = fcw + (size_t)e * D_ * F2_;
    const int tokA = toks[a_m];
    const float* apx = (tokA >= 0) ? (h2 + (size_t)tokA * D_ + a_kh) : nullptr;
    const float* bpx = W + (size_t)(kg*4) * F2_ + col0 + n_l;
    const int kcA = (tid & 1) * 2;

    float4 a0, a1, a2, a3; float b1v[4], b2v[4];
    a0 = make_float4(0,0,0,0); a1 = a0; a2 = a0; a3 = a0;
    if (apx) {
        a0 = *(const float4*)(apx);     a1 = *(const float4*)(apx + 4);
        a2 = *(const float4*)(apx + 8); a3 = *(const float4*)(apx + 12);
    }
    #pragma unroll
    for (int j=0;j<4;j++) { b1v[j] = bpx[(size_t)j*F2_]; b2v[j] = bpx[(size_t)j*F2_ + F_]; }

    for (int k0 = 0; k0 < D_; k0 += 32) {
        __syncthreads();
        short8 c0, c1;
        short4v cb1, cb2;
        cvt16(a0,a1,a2,a3,c0,c1);
        #pragma unroll
        for (int j=0;j<4;j++) { cb1[j] = f2bf(b1v[j]); cb2[j] = f2bf(b2v[j]); }
        *(short8*)&As[((kcA  )*128 + a_m)*8] = c0;
        *(short8*)&As[((kcA+1)*128 + a_m)*8] = c1;
        *(short4v*)&B1s[n_l*40 + kg*4] = cb1;
        *(short4v*)&B2s[n_l*40 + kg*4] = cb2;
        __syncthreads();
        if (k0 + 32 < D_) {
            if (apx) {
                const float* ap2 = apx + k0 + 32;
                a0 = *(const float4*)(ap2);     a1 = *(const float4*)(ap2 + 4);
                a2 = *(const float4*)(ap2 + 8); a3 = *(const float4*)(ap2 + 12);
            }
            const float* bp2 = bpx + (size_t)(k0+32) * F2_;
            #pragma unroll
            for (int j=0;j<4;j++) { b1v[j] = bp2[(size_t)j*F2_]; b2v[j] = bp2[(size_t)j*F2_ + F_]; }
        }
        FragU fa[4], fb1, fb2;
        #pragma unroll
        for (int i=0;i<4;i++) fa[i].s = *(short8*)&As[(quad*128 + wm*64 + i*16 + lm)*8];
        fb1.s = *(short8*)&B1s[(wn*16 + lm)*40 + quad*8];
        fb2.s = *(short8*)&B2s[(wn*16 + lm)*40 + quad*8];
        #pragma unroll
        for (int i=0;i<4;i++) {
            acc1[i] = __builtin_amdgcn_mfma_f32_16x16x32_bf16(fa[i].b, fb1.b, acc1[i], 0,0,0);
            acc2[i] = __builtin_amdgcn_mfma_f32_16x16x32_bf16(fa[i].b, fb2.b, acc2[i], 0,0,0);
        }
    }
    {
        int col = col0 + wn*16 + lm;
        float b1 = fcb[(size_t)e*F2_ + col];
        float b2 = fcb[(size_t)e*F2_ + F_ + col];
        #pragma unroll
        for (int i=0;i<4;i++)
            #pragma unroll
            for (int r=0;r<4;r++) {
                int tk = toks[wm*64 + i*16 + quad*4 + r];
                if (tk < 0) continue;
                float v1 = acc1[i][r] + b1;
                float v2 = acc2[i][r] + b2;
                float g = v2 * 0.5f * (1.0f + erff(v2 * 0.70710678118654752f));
                aout[(size_t)tk*F_ + col] = v1 * g;
            }
    }
}

// ===================== MFMA flash attention (round-3, unchanged) =====================
__global__ __launch_bounds__(128) void flash_attn(
    const float* __restrict__ qkv, const int* __restrict__ ids,
    float* __restrict__ attnout)
{
    const int h  = blockIdx.y;
    const int q0 = blockIdx.x * 32;
    const int tid = threadIdx.x;
    const int lane = tid & 63, w = tid >> 6;
    const int quad = lane >> 4, lm = lane & 15;

    __shared__ __align__(16) short Qs[32*72];
    __shared__ __align__(16) short Ks[64*72];
    __shared__ __align__(16) short Vt[64*72];
    __shared__ __align__(16) short Ps[2][16*72];
    __shared__ int globf[32];

    {
        int row = tid >> 2, c = (tid & 3) * 16;
        const float* qp = qkv + (size_t)(q0 + row) * D3_ + h * HD_ + c;
        float4 f0 = *(const float4*)(qp);
        float4 f1 = *(const float4*)(qp + 4);
        float4 f2 = *(const float4*)(qp + 8);
        float4 f3 = *(const float4*)(qp + 12);
        short8 s0, s1;
        cvt16(f0, f1, f2, f3, s0, s1);
        *(short8*)&Qs[row*72 + c]     = s0;
        *(short8*)&Qs[row*72 + c + 8] = s1;
    }
    if (tid < 32) {
        int id = ids[q0 + tid];
        globf[tid] = (id >= 2 && id <= 7) ? 1 : 0;
    }
    __syncthreads();

    FragU QA[2];
    #pragma unroll
    for (int s = 0; s < 2; s++)
        QA[s].s = *(short8*)&Qs[(w*16 + lm)*72 + s*32 + quad*8];

    int any = 0;
    #pragma unroll
    for (int i = 0; i < 32; i++) any |= globf[i];
    const int nt = any ? (T_/64) : ((q0 + 31) >> 6) + 1;

    int gq[4]; int qidx[4];
    #pragma unroll
    for (int r = 0; r < 4; r++) {
        int ql = w*16 + quad*4 + r;
        qidx[r] = q0 + ql;
        gq[r] = globf[ql];
    }

    float mrow[4] = {-1e30f, -1e30f, -1e30f, -1e30f};
    float lrow[4] = {0.f, 0.f, 0.f, 0.f};
    floatx4 Oacc[4];
    #pragma unroll
    for (int n = 0; n < 4; n++) Oacc[n] = (floatx4){0.f, 0.f, 0.f, 0.f};

    for (int kt = 0; kt < nt; kt++) {
        __syncthreads();
        #pragma unroll
        for (int rep = 0; rep < 2; rep++) {
            int key = (tid >> 2) + rep*32;
            int c = (tid & 3) * 16;
            const float* kp = qkv + (size_t)(kt*64 + key) * D3_ + D_ + h*HD_ + c;
            float4 f0 = *(const float4*)(kp);
            float4 f1 = *(const float4*)(kp + 4);
            float4 f2 = *(const float4*)(kp + 8);
            float4 f3 = *(const float4*)(kp + 12);
            short8 s0, s1;
            cvt16(f0, f1, f2, f3, s0, s1);
            *(short8*)&Ks[key*72 + c]     = s0;
            *(short8*)&Ks[key*72 + c + 8] = s1;
        }
        #pragma unroll
        for (int rep = 0; rep < 8; rep++) {
            int lin = tid + rep*128;
            int key = lin >> 4;
            int c = (lin & 15) * 4;
            const float* vp = qkv + (size_t)(kt*64 + key) * D3_ + 2*D_ + h*HD_ + c;
            float4 f = *(const float4*)vp;
            Vt[(c+0)*72 + key] = f2bf(f.x);
            Vt[(c+1)*72 + key] = f2bf(f.y);
            Vt[(c+2)*72 + key] = f2bf(f.z);
            Vt[(c+3)*72 + key] = f2bf(f.w);
        }
        __syncthreads();

        floatx4 Sv[4];
        #pragma unroll
        for (int n = 0; n < 4; n++) {
            Sv[n] = (floatx4){0.f, 0.f, 0.f, 0.f};
            #pragma unroll
            for (int s = 0; s < 2; s++) {
                FragU KB;
                KB.s = *(short8*)&Ks[(n*16 + lm)*72 + s*32 + quad*8];
                Sv[n] = __builtin_amdgcn_mfma_f32_16x16x32_bf16(QA[s].b, KB.b, Sv[n], 0, 0, 0);
            }
        }
        #pragma unroll
        for (int n = 0; n < 4; n++) {
            int key = kt*64 + n*16 + lm;
            #pragma unroll
            for (int r = 0; r < 4; r++) {
                float v = Sv[n][r] * 0.125f;
                if (!gq[r] && key > qidx[r]) v = -1e30f;
                Sv[n][r] = v;
            }
        }
        float mnew[4], alpha[4], tsum[4];
        #pragma unroll
        for (int r = 0; r < 4; r++) {
            float tm = fmaxf(fmaxf(Sv[0][r], Sv[1][r]), fmaxf(Sv[2][r], Sv[3][r]));
            #pragma unroll
            for (int x = 1; x < 16; x <<= 1) tm = fmaxf(tm, __shfl_xor(tm, x));
            mnew[r] = fmaxf(mrow[r], tm);
            alpha[r] = __expf(mrow[r] - mnew[r]);
            mrow[r] = mnew[r];
            tsum[r] = 0.f;
        }
        #pragma unroll
        for (int n = 0; n < 4; n++) {
            #pragma unroll
            for (int r = 0; r < 4; r++) {
                float p = __expf(Sv[n][r] - mnew[r]);
                tsum[r] += p;
                Ps[w][(quad*4 + r)*72 + n*16 + lm] = f2bf(p);
            }
        }
        #pragma unroll
        for (int r = 0; r < 4; r++) {
            #pragma unroll
            for (int x = 1; x < 16; x <<= 1) tsum[r] += __shfl_xor(tsum[r], x);
            lrow[r] = lrow[r] * alpha[r] + tsum[r];
        }
        #pragma unroll
        for (int n = 0; n < 4; n++)
            #pragma unroll
            for (int r = 0; r < 4; r++) Oacc[n][r] *= alpha[r];

        #pragma unroll
        for (int s = 0; s < 2; s++) {
            FragU PA;
            PA.s = *(short8*)&Ps[w][lm*72 + s*32 + quad*8];
            #pragma unroll
            for (int n = 0; n < 4; n++) {
                FragU VB;
                VB.s = *(short8*)&Vt[(n*16 + lm)*72 + s*32 + quad*8];
                Oacc[n] = __builtin_amdgcn_mfma_f32_16x16x32_bf16(PA.b, VB.b, Oacc[n], 0, 0, 0);
            }
        }
    }

    #pragma unroll
    for (int n = 0; n < 4; n++)
        #pragma unroll
        for (int r = 0; r < 4; r++) {
            float o = Oacc[n][r] / lrow[r];
            attnout[(size_t)qidx[r]*D_ + h*HD_ + n*16 + lm] = o;
        }
}

// ===================== epilogues =====================
__global__ __launch_bounds__(256) void ep_attn(
    const float* __restrict__ x, const float* __restrict__ sacc,
    const float* __restrict__ aob, float* __restrict__ x2)
{
    int row = blockIdx.x, tid = threadIdx.x;
    float4 xv = ((const float4*)(x + (size_t)row*D_))[tid];
    float4 sv = ((const float4*)(sacc + (size_t)row*D_))[tid];
    float4 bv = ((const float4*)aob)[tid];
    float4 o;
    o.x = xv.x + sv.x + bv.x; o.y = xv.y + sv.y + bv.y;
    o.z = xv.z + sv.z + bv.z; o.w = xv.w + sv.w + bv.w;
    ((float4*)(x2 + (size_t)row*D_))[tid] = o;
}

__global__ __launch_bounds__(256) void ep_moe(
    const float* __restrict__ x2, const float* __restrict__ sacc,
    const float* __restrict__ eob, const float* __restrict__ gw,
    const int* __restrict__ gi, float* __restrict__ out)
{
    int row = blockIdx.x, tid = threadIdx.x;
    float g = gw[row];
    int e = gi[row];
    float4 xv = ((const float4*)(x2 + (size_t)row*D_))[tid];
    float4 sv = ((const float4*)(sacc + (size_t)row*D_))[tid];
    float4 bv = ((const float4*)(eob + (size_t)e*D_))[tid];
    float4 o;
    o.x = xv.x + g*(sv.x + bv.x); o.y = xv.y + g*(sv.y + bv.y);
    o.z = xv.z + g*(sv.z + bv.z); o.w = xv.w + g*(sv.w + bv.w);
    ((float4*)(out + (size_t)row*D_))[tid] = o;
}

// ===================== small kernels =====================
__global__ __launch_bounds__(256) void ln_kernel(
    const float* __restrict__ x, const float* __restrict__ w,
    const float* __restrict__ b, float* __restrict__ out)
{
    const int row = blockIdx.x, tid = threadIdx.x;
    const int lane = tid & 63, wave = tid >> 6;
    float4 v = ((const float4*)(x + (size_t)row * D_))[tid];
    float s  = v.x + v.y + v.z + v.w;
    float sq = v.x*v.x + v.y*v.y + v.z*v.z + v.w*v.w;
    #pragma unroll
    for (int off = 32; off; off >>= 1) {
        s  += __shfl_down(s, off);
        sq += __shfl_down(sq, off);
    }
    __shared__ float rs[4], rq[4], mv[2];
    if (lane == 0) { rs[wave] = s; rq[wave] = sq; }
    __syncthreads();
    if (tid == 0) {
        float ts = rs[0]+rs[1]+rs[2]+rs[3];
        float tq = rq[0]+rq[1]+rq[2]+rq[3];
        float mean = ts * (1.0f / D_);
        float var  = tq * (1.0f / D_) - mean*mean;
        mv[0] = mean; mv[1] = rsqrtf(var + 1e-5f);
    }
    __syncthreads();
    float mean = mv[0], rstd = mv[1];
    float4 wv = ((const float4*)w)[tid];
    float4 bv = ((const float4*)b)[tid];
    float4 o;
    o.x = (v.x-mean)*rstd*wv.x + bv.x;
    o.y = (v.y-mean)*rstd*wv.y + bv.y;
    o.z = (v.z-mean)*rstd*wv.z + bv.z;
    o.w = (v.w-mean)*rstd*wv.w + bv.w;
    ((float4*)(out + (size_t)row * D_))[tid] = o;
}

__global__ __launch_bounds__(256) void rope_kernel(float* __restrict__ qkv)
{
    int gid = blockIdx.x * 256 + threadIdx.x;
    int t = gid >> 9;
    int r = gid & 511;
    int h = r >> 5;
    int d = r & 31;
    float inv = powf(10000.0f, -(float)d * (1.0f/32.0f));
    float fr = (float)t * inv;
    float s, c;
    sincosf(fr, &s, &c);
    float* base = qkv + (size_t)t*D3_ + h*HD_ + d;
    float q1 = base[0], q2 = base[32];
    base[0]  = q1*c - q2*s;
    base[32] = q1*s + q2*c;
    float* kb = base + D_;
    float k1 = kb[0], k2 = kb[32];
    kb[0]  = k1*c - k2*s;
    kb[32] = k1*s + k2*c;
}

__global__ __launch_bounds__(256) void ln2_gate_kernel(
    const float* __restrict__ x2, const float* __restrict__ w,
    const float* __restrict__ b, const float* __restrict__ gwm,
    const float* __restrict__ gbv, float* __restrict__ h2,
    int* __restrict__ gi, float* __restrict__ gw)
{
    const int row = blockIdx.x, tid = threadIdx.x;
    const int lane = tid & 63, wave = tid >> 6;
    float4 v = ((const float4*)(x2 + (size_t)row * D_))[tid];
    float s  = v.x + v.y + v.z + v.w;
    float sq = v.x*v.x + v.y*v.y + v.z*v.z + v.w*v.w;
    #pragma unroll
    for (int off = 32; off; off >>= 1) {
        s  += __shfl_down(s, off);
        sq += __shfl_down(sq, off);
    }
    __shared__ float rs[4], rq[4], mv[2];
    if (lane == 0) { rs[wave] = s; rq[wave] = sq; }
    __syncthreads();
    if (tid == 0) {
        float ts = rs[0]+rs[1]+rs[2]+rs[3];
        float tq = rq[0]+rq[1]+rq[2]+rq[3];
        float mean = ts * (1.0f / D_);
        float var  = tq * (1.0f / D_) - mean*mean;
        mv[0] = mean; mv[1] = rsqrtf(var + 1e-5f);
    }
    __syncthreads();
    float mean = mv[0], rstd = mv[1];
    float4 wv = ((const float4*)w)[tid];
    float4 bv = ((const float4*)b)[tid];
    float hv[4];
    hv[0] = (v.x-mean)*rstd*wv.x + bv.x;
    hv[1] = (v.y-mean)*rstd*wv.y + bv.y;
    hv[2] = (v.z-mean)*rstd*wv.z + bv.z;
    hv[3] = (v.w-mean)*rstd*wv.w + bv.w;
    float4 o; o.x=hv[0]; o.y=hv[1]; o.z=hv[2]; o.w=hv[3];
    ((float4*)(h2 + (size_t)row * D_))[tid] = o;

    float acc[E_] = {};
    int c = tid * 4;
    #pragma unroll
    for (int j = 0; j < 4; j++) {
        const float* gr = gwm + (size_t)(c+j) * E_;
        #pragma unroll
        for (int e = 0; e < E_; e++) acc[e] += hv[j] * gr[e];
    }
    #pragma unroll
    for (int off = 32; off; off >>= 1)
        #pragma unroll
        for (int e = 0; e < E_; e++) acc[e] += __shfl_down(acc[e], off);
    __shared__ float gred[4][E_];
    if (lane == 0)
        for (int e = 0; e < E_; e++) gred[wave][e] = acc[e];
    __syncthreads();
    if (tid == 0) {
        float lg[E_];
        float mxl = -FLT_MAX; int mi = 0;
        for (int e = 0; e < E_; e++)
            lg[e] = gred[0][e]+gred[1][e]+gred[2][e]+gred[3][e] + gbv[e];
        for (int e = 0; e < E_; e++)
            if (lg[e] > mxl) { mxl = lg[e]; mi = e; }
        float ssum = 0.f;
        for (int e = 0; e < E_; e++) ssum += expf(lg[e] - mxl);
        gi[row] = mi;
        gw[row] = 1.0f / ssum;
    }
}

__global__ void route_kernel(const int* __restrict__ gi,
                             int* __restrict__ offs, int* __restrict__ perm)
{
    __shared__ int cnt[E_], c2[E_], off[E_+1];
    const int tid = threadIdx.x;
    if (tid < E_) { cnt[tid] = 0; c2[tid] = 0; }
    __syncthreads();
    int e = gi[tid];
    atomicAdd(&cnt[e], 1);
    __syncthreads();
    if (tid == 0) {
        off[0] = 0;
        for (int i = 0; i < E_; i++) off[i+1] = off[i] + cnt[i];
        for (int i = 0; i <= E_; i++) offs[i] = off[i];
    }
    __syncthreads();
    int r = atomicAdd(&c2[e], 1);
    perm[off[e] + r] = tid;
}

__global__ void loss_kernel(const int* __restrict__ gi,
                            const float* __restrict__ gw, float* __restrict__ out)
{
    __shared__ float ss[E_], sc[E_];
    const int tid = threadIdx.x;
    if (tid < E_) { ss[tid] = 0.f; sc[tid] = 0.f; }
    __syncthreads();
    for (int t = tid; t < T_; t += 256) {
        int e = gi[t];
        atomicAdd(&ss[e], gw[t]);
        atomicAdd(&sc[e], 1.0f);
    }
    __syncthreads();
    if (tid == 0) {
        float loss = 0.f;
        for (int e = 0; e < E_; e++) {
            float u = ss[e] / (sc[e] + 1e-8f);
            float d = u - 0.125f;
            loss += d * d;
        }
        out[(size_t)T_ * D_] = loss;
    }
}

extern "C" void kernel_launch(void* const* d_in, const int* in_sizes, int n_in,
                              void* d_out, int out_size, void* d_ws, size_t ws_size,
                              hipStream_t stream)
{
    const float* x     = (const float*)d_in[0];
    const int*   ids   = (const int*)d_in[1];
    const float* ln1w  = (const float*)d_in[2];
    const float* ln1b  = (const float*)d_in[3];
    const float* qkvw  = (const float*)d_in[4];
    const float* qkvb  = (const float*)d_in[5];
    const float* aow   = (const float*)d_in[6];
    const float* aob   = (const float*)d_in[7];
    const float* ln2w  = (const float*)d_in[8];
    const float* ln2b  = (const float*)d_in[9];
    const float* gatew = (const float*)d_in[10];
    const float* gateb = (const float*)d_in[11];
    const float* fcw   = (const float*)d_in[12];
    const float* fcb   = (const float*)d_in[13];
    const float* eoutw = (const float*)d_in[14];
    const float* eoutb = (const float*)d_in[15];
    float* out = (float*)d_out;
    float* ws  = (float*)d_ws;

    float* h    = ws + WS_H;      // reused as SACC after qkv GEMM
    float* sacc = ws + WS_H;
    float* qkv  = ws + WS_QKV;
    float* attn = ws + WS_ATTN;
    float* x2   = ws + WS_X2;
    float* h2   = ws + WS_H2;
    float* abuf = ws + WS_A;
    float* gw   = ws + WS_GW;
    int*   gi   = (int*)(ws + WS_GI);
    int*   offs = (int*)(ws + WS_OFFS);
    int*   perm = (int*)(ws + WS_PERM);

    // 1. LN1
    ln_kernel<<<T_, 256, 0, stream>>>(x, ln1w, ln1b, h);
    // 2. QKV projection (MFMA, pipelined)
    gemm_mfma_full<<<dim3(D3_/64, T_/128), 256, 0, stream>>>(
        h, D_, qkvw, D3_, qkvb, qkv, D3_, D_);
    // 3. RoPE
    rope_kernel<<<(T_*H_*32)/256, 256, 0, stream>>>(qkv);
    // 4. MFMA flash attention
    flash_attn<<<dim3(T_/32, H_), 128, 0, stream>>>(qkv, ids, attn);
    // 5. zero split-K accumulator
    hipMemsetAsync(sacc, 0, (size_t)T_*D_*sizeof(float), stream);
    // 6. attn output projection (MFMA, split-K=4)
    gemm_mfma_acc<<<dim3(D_/64, T_/128, 4), 256, 0, stream>>>(
        attn, D_, aow, D_, 0, nullptr, nullptr, sacc, D_, D_, 4);
    // 7. residual + bias
    ep_attn<<<T_, 256, 0, stream>>>(x, sacc, aob, x2);
    // 8. LN2 + gate
    ln2_gate_kernel<<<T_, 256, 0, stream>>>(x2, ln2w, ln2b, gatew, gateb, h2, gi, gw);
    // 9. routing
    route_kernel<<<1, T_, 0, stream>>>(gi, offs, perm);
    // 10. expert fc + GLU (MFMA, BN=32 pairs, pipelined)
    moe_fc_mfma<<<dim3(F_/32, T_/128, E_), 256, 0, stream>>>(h2, fcw, fcb, offs, perm, abuf);
    // 11. re-zero accumulator
    hipMemsetAsync(sacc, 0, (size_t)T_*D_*sizeof(float), stream);
    // 12. expert out (MFMA, split-K=4, routed)
    gemm_mfma_acc<<<dim3(D_/64, T_/128, 4*E_), 256, 0, stream>>>(
        abuf, F_, eoutw, D_, (long)F_*D_, offs, perm, sacc, D_, F_, 4);
    // 13. residual + gate scale + bias
    ep_moe<<<T_, 256, 0, stream>>>(x2, sacc, eoutb, gw, gi, out);
    // 14. aux loss
    loss_kernel<<<1, 256, 0, stream>>>(gi, gw, out);
}